// Round 1
// baseline (1674.624 us; speedup 1.0000x reference)
//
#include <hip/hip_runtime.h>

typedef __attribute__((ext_vector_type(8))) short short8;
typedef __attribute__((ext_vector_type(4))) float f32x4;

#define T_SEQ 2048
#define D_DIM 1024
#define B_DIM 4
#define M_ROWS 8192
#define CT 32
#define NC (T_SEQ / CT)

__device__ __forceinline__ unsigned short f2bf_rne(float v) {
    unsigned int u = __float_as_uint(v);
    unsigned int r = (u + 0x7fffu + ((u >> 16) & 1u)) >> 16;
    return (unsigned short)r;
}
__device__ __forceinline__ float bf2f(unsigned short u) {
    return __uint_as_float(((unsigned int)u) << 16);
}

// ---------------- weight transpose + bf16 split conversion ----------------
// W: (K x N) f32 row-major  ->  WT hi/lo: (N x K) bf16 bits row-major
__global__ void transpose_cvt(const float* __restrict__ W, int K, int N,
                              unsigned short* __restrict__ hi,
                              unsigned short* __restrict__ lo) {
    __shared__ float tile[32][33];
    int kt = blockIdx.y * 32, nt = blockIdx.x * 32;
    int c = threadIdx.x & 31, r0 = threadIdx.x >> 5;  // 8 rows per pass
#pragma unroll
    for (int i = 0; i < 4; i++) {
        int r = r0 + i * 8;
        tile[r][c] = W[(size_t)(kt + r) * N + nt + c];
    }
    __syncthreads();
#pragma unroll
    for (int i = 0; i < 4; i++) {
        int n = r0 + i * 8;
        float v = tile[c][n];  // = W[kt+c][nt+n]
        size_t o = (size_t)(nt + n) * K + kt + c;
        unsigned short h = f2bf_rne(v);
        hi[o] = h;
        if (lo) {
            lo[o] = f2bf_rne(v - bf2f(h));
        }
    }
}

// ---------------- GEMM: C = A @ W + bias, W given as WT (N x K) bf16 ----------------
// A element (m,k): k < splitK ? A0[m*lda0+k] : A1[m*lda1+(k-splitK)]
template <bool SPLIT, int ACT>
__global__ __launch_bounds__(256, 2) void gemm_kernel(
    const float* __restrict__ A0, int lda0,
    const float* __restrict__ A1, int lda1, int splitK,
    const unsigned short* __restrict__ BThi,
    const unsigned short* __restrict__ BTlo,
    const float* __restrict__ bias,
    float* __restrict__ C, int ldc,
    int M, int N, int K) {
    constexpr int BM = 128, BN = 128, BK = 32, PAD = 40;
    __shared__ unsigned short sAhi[BM * PAD];
    __shared__ unsigned short sAlo[SPLIT ? BM * PAD : 1];
    __shared__ unsigned short sBhi[BN * PAD];
    __shared__ unsigned short sBlo[SPLIT ? BN * PAD : 1];

    int tid = threadIdx.x;
    int lane = tid & 63, wave = tid >> 6;
    int wr = wave >> 1, wc = wave & 1;
    int row0 = blockIdx.y * BM, col0 = blockIdx.x * BN;
    int lr = lane & 15, kc = lane >> 4;

    int arow = tid >> 1;             // 0..127
    int akb = (tid & 1) * 16;        // k offset within BK
    int am = row0 + arow;

    f32x4 acc[4][4] = {};
    float4 aexp[4];
    uint4 bhiR[2], bloR[2];

    auto loadA = [&](int kt) {
        int kk = kt * BK + akb;
        const float* src;
        if (kk < splitK) src = A0 + (size_t)am * lda0 + kk;
        else             src = A1 + (size_t)am * lda1 + (kk - splitK);
#pragma unroll
        for (int q = 0; q < 4; q++)
            aexp[q] = *reinterpret_cast<const float4*>(src + q * 4);
    };
    auto loadB = [&](int kt) {
        size_t base = (size_t)(col0 + (tid >> 1)) * K + kt * BK + (tid & 1) * 16;
        const uint4* ph = reinterpret_cast<const uint4*>(BThi + base);
        bhiR[0] = ph[0];
        bhiR[1] = ph[1];
        if constexpr (SPLIT) {
            const uint4* pl = reinterpret_cast<const uint4*>(BTlo + base);
            bloR[0] = pl[0];
            bloR[1] = pl[1];
        }
    };
    auto storeAB = [&]() {
        int aoff = arow * PAD + akb;
#pragma unroll
        for (int q = 0; q < 4; q++) {
            float4 v = aexp[q];
            unsigned short hx = f2bf_rne(v.x), hy = f2bf_rne(v.y);
            unsigned short hz = f2bf_rne(v.z), hw = f2bf_rne(v.w);
            uint2 hv;
            hv.x = (unsigned int)hx | ((unsigned int)hy << 16);
            hv.y = (unsigned int)hz | ((unsigned int)hw << 16);
            *reinterpret_cast<uint2*>(&sAhi[aoff + q * 4]) = hv;
            if constexpr (SPLIT) {
                unsigned short lx = f2bf_rne(v.x - bf2f(hx));
                unsigned short ly = f2bf_rne(v.y - bf2f(hy));
                unsigned short lz = f2bf_rne(v.z - bf2f(hz));
                unsigned short lw = f2bf_rne(v.w - bf2f(hw));
                uint2 lv;
                lv.x = (unsigned int)lx | ((unsigned int)ly << 16);
                lv.y = (unsigned int)lz | ((unsigned int)lw << 16);
                *reinterpret_cast<uint2*>(&sAlo[aoff + q * 4]) = lv;
            }
        }
        int boff = (tid >> 1) * PAD + (tid & 1) * 16;
        *reinterpret_cast<uint4*>(&sBhi[boff]) = bhiR[0];
        *reinterpret_cast<uint4*>(&sBhi[boff + 8]) = bhiR[1];
        if constexpr (SPLIT) {
            *reinterpret_cast<uint4*>(&sBlo[boff]) = bloR[0];
            *reinterpret_cast<uint4*>(&sBlo[boff + 8]) = bloR[1];
        }
    };

    int nkt = K / BK;
    loadA(0);
    loadB(0);
    for (int kt = 0; kt < nkt; ++kt) {
        __syncthreads();
        storeAB();
        __syncthreads();
        if (kt + 1 < nkt) { loadA(kt + 1); loadB(kt + 1); }

        short8 ahi[4], alo[4], bhi[4], blo[4];
#pragma unroll
        for (int mi = 0; mi < 4; mi++) {
            int r = wr * 64 + mi * 16 + lr;
            ahi[mi] = *reinterpret_cast<const short8*>(&sAhi[r * PAD + kc * 8]);
            if constexpr (SPLIT)
                alo[mi] = *reinterpret_cast<const short8*>(&sAlo[r * PAD + kc * 8]);
        }
#pragma unroll
        for (int ni = 0; ni < 4; ni++) {
            int c = wc * 64 + ni * 16 + lr;
            bhi[ni] = *reinterpret_cast<const short8*>(&sBhi[c * PAD + kc * 8]);
            if constexpr (SPLIT)
                blo[ni] = *reinterpret_cast<const short8*>(&sBlo[c * PAD + kc * 8]);
        }
#pragma unroll
        for (int mi = 0; mi < 4; mi++)
#pragma unroll
            for (int ni = 0; ni < 4; ni++) {
                acc[mi][ni] = __builtin_amdgcn_mfma_f32_16x16x32_bf16(ahi[mi], bhi[ni], acc[mi][ni], 0, 0, 0);
                if constexpr (SPLIT) {
                    acc[mi][ni] = __builtin_amdgcn_mfma_f32_16x16x32_bf16(ahi[mi], blo[ni], acc[mi][ni], 0, 0, 0);
                    acc[mi][ni] = __builtin_amdgcn_mfma_f32_16x16x32_bf16(alo[mi], bhi[ni], acc[mi][ni], 0, 0, 0);
                }
            }
    }

    float bv[4];
#pragma unroll
    for (int ni = 0; ni < 4; ni++) bv[ni] = bias[col0 + wc * 64 + ni * 16 + lr];
#pragma unroll
    for (int mi = 0; mi < 4; mi++) {
        int rbase = row0 + wr * 64 + mi * 16 + kc * 4;
#pragma unroll
        for (int ni = 0; ni < 4; ni++) {
            int c = col0 + wc * 64 + ni * 16 + lr;
#pragma unroll
            for (int i = 0; i < 4; i++) {
                float v = acc[mi][ni][i] + bv[ni];
                if (ACT == 1) v = 0.98f / (1.0f + expf(-v)) + 0.01f;
                C[(size_t)(rbase + i) * ldc + c] = v;
            }
        }
    }
}

// ---------------- scan: per-step coefficients ----------------
__device__ __forceinline__ void step_coefs(float lre, float lim, float dt,
                                           float& are, float& aim,
                                           float& fre, float& fim) {
    float zr = lre * dt, zi = lim * dt;
    float er = expm1f(zr);
    float ex = er + 1.0f;
    float cy = cosf(zi), sy = sinf(zi);
    float sh = sinf(0.5f * zi);
    are = ex * cy;
    aim = ex * sy;
    float nr = er * cy - 2.0f * sh * sh;
    float ni = ex * sy;
    float r2 = zr * zr + zi * zi;
    float pr, pi;
    if (r2 > 1e-14f) {  // |z| > 1e-7
        float inv = 1.0f / r2;
        pr = (nr * zr + ni * zi) * inv;
        pi = (ni * zr - nr * zi) * inv;
    } else {
        pr = 1.0f + 0.5f * zr + (zr * zr - zi * zi) * (1.0f / 6.0f);
        pi = 0.5f * zi + (zr * zi) * (1.0f / 3.0f);
    }
    fre = dt * pr;
    fim = dt * pi;
}

__device__ __forceinline__ void lam_of(const float* decay_re, const float* decay_im,
                                       int d, float& lre, float& lim) {
    float x = decay_re[d];
    float sp = fmaxf(x, 0.0f) + log1pf(expf(-fabsf(x)));
    lre = -sp;
    lim = decay_im[d];
}

// phase 1: per-chunk (A, B) summaries
__global__ void scan_phase1(const float* __restrict__ x_in,
                            const float* __restrict__ dt_seq,
                            const float* __restrict__ decay_re,
                            const float* __restrict__ decay_im,
                            float4* __restrict__ S) {
    int gw = (blockIdx.x * blockDim.x + threadIdx.x) >> 6;
    int lane = threadIdx.x & 63;
    int d64 = gw & 15;
    int c = (gw >> 4) & (NC - 1);
    int b = gw >> 10;
    int d = d64 * 64 + lane;
    float lre, lim;
    lam_of(decay_re, decay_im, d, lre, lim);
    float Are = 1.f, Aim = 0.f, Bre = 0.f, Bim = 0.f;
    for (int j = 0; j < CT; j++) {
        int t = c * CT + j;
        float dt = dt_seq[b * T_SEQ + t];
        float are, aim, fre, fim;
        step_coefs(lre, lim, dt, are, aim, fre, fim);
        size_t off = ((size_t)(b * T_SEQ + t)) * 2048;
        float xr = x_in[off + d];
        float xi = x_in[off + 1024 + d];
        float xsr = xr * fre - xi * fim;
        float xsi = xr * fim + xi * fre;
        float nbr = are * Bre - aim * Bim + xsr;
        float nbi = are * Bim + aim * Bre + xsi;
        Bre = nbr; Bim = nbi;
        float nar = are * Are - aim * Aim;
        float nai = are * Aim + aim * Are;
        Are = nar; Aim = nai;
    }
    S[(size_t)(b * NC + c) * D_DIM + d] = make_float4(Are, Aim, Bre, Bim);
}

// phase 2: sequential prefix over chunks; Pre[c] = h at chunk start
__global__ void scan_phase2(const float4* __restrict__ S,
                            const float* __restrict__ h0_re,
                            const float* __restrict__ h0_im,
                            float2* __restrict__ Pre) {
    int idx = blockIdx.x * blockDim.x + threadIdx.x;  // B*D = 4096
    int b = idx >> 10, d = idx & 1023;
    float Are = 1.f, Aim = 0.f;
    float Bre = h0_re[d], Bim = h0_im[d];
    for (int c = 0; c < NC; c++) {
        Pre[(size_t)(b * NC + c) * D_DIM + d] = make_float2(Bre, Bim);
        float4 s = S[(size_t)(b * NC + c) * D_DIM + d];
        float nAre = s.x * Are - s.y * Aim;
        float nAim = s.x * Aim + s.y * Are;
        float nBre = s.x * Bre - s.y * Bim + s.z;
        float nBim = s.x * Bim + s.y * Bre + s.w;
        Are = nAre; Aim = nAim; Bre = nBre; Bim = nBim;
    }
}

// phase 3: recompute within-chunk recurrence from prefix, write state_cat
__global__ void scan_phase3(const float* __restrict__ x_in,
                            const float* __restrict__ dt_seq,
                            const float* __restrict__ decay_re,
                            const float* __restrict__ decay_im,
                            const float2* __restrict__ Pre,
                            float* __restrict__ state) {
    int gw = (blockIdx.x * blockDim.x + threadIdx.x) >> 6;
    int lane = threadIdx.x & 63;
    int d64 = gw & 15;
    int c = (gw >> 4) & (NC - 1);
    int b = gw >> 10;
    int d = d64 * 64 + lane;
    float lre, lim;
    lam_of(decay_re, decay_im, d, lre, lim);
    float2 h = Pre[(size_t)(b * NC + c) * D_DIM + d];
    float hre = h.x, him = h.y;
    for (int j = 0; j < CT; j++) {
        int t = c * CT + j;
        float dt = dt_seq[b * T_SEQ + t];
        float are, aim, fre, fim;
        step_coefs(lre, lim, dt, are, aim, fre, fim);
        size_t off = ((size_t)(b * T_SEQ + t)) * 2048;
        float xr = x_in[off + d];
        float xi = x_in[off + 1024 + d];
        float xsr = xr * fre - xi * fim;
        float xsi = xr * fim + xi * fre;
        float nre = are * hre - aim * him + xsr;
        float nim = are * him + aim * hre + xsi;
        hre = nre; him = nim;
        state[off + d] = hre;
        state[off + 1024 + d] = him;
    }
}

extern "C" void kernel_launch(void* const* d_in, const int* in_sizes, int n_in,
                              void* d_out, int out_size, void* d_ws, size_t ws_size,
                              hipStream_t stream) {
    const float* x_re = (const float*)d_in[0];
    const float* x_im = (const float*)d_in[1];
    const float* dt_seq = (const float*)d_in[2];
    const float* decay_re = (const float*)d_in[3];
    const float* decay_im = (const float*)d_in[4];
    const float* h0_re = (const float*)d_in[5];
    const float* h0_im = (const float*)d_in[6];
    const float* W_mix = (const float*)d_in[7];
    const float* b_mix = (const float*)d_in[8];
    const float* W_out = (const float*)d_in[9];
    const float* b_out = (const float*)d_in[10];
    const float* W_gc = (const float*)d_in[11];
    const float* b_gc = (const float*)d_in[12];
    const float* W_gate = (const float*)d_in[13];
    const float* b_gate = (const float*)d_in[14];
    float* out = (float*)d_out;

    char* ws = (char*)d_ws;
    float* x_in = (float*)(ws);                                   // 64 MB (reused as gate_ctx)
    float* state = (float*)(ws + 67108864ull);                    // 64 MB
    float4* S = (float4*)(ws + 134217728ull);                     // 4 MB
    float2* Pre = (float2*)(ws + 138412032ull);                   // 2 MB
    unsigned short* WmixT_hi = (unsigned short*)(ws + 140509184ull);
    unsigned short* WmixT_lo = WmixT_hi + 4194304;                // 2048*2048
    unsigned short* WoutT_hi = WmixT_lo + 4194304;
    unsigned short* WoutT_lo = WoutT_hi + 4194304;
    unsigned short* WgcT = WoutT_lo + 4194304;                    // 2048 x 4096
    unsigned short* WgateT = WgcT + 8388608;                      // 1024 x 2048

    dim3 blk(256);

    transpose_cvt<<<dim3(64, 64), blk, 0, stream>>>(W_mix, 2048, 2048, WmixT_hi, WmixT_lo);
    transpose_cvt<<<dim3(64, 64), blk, 0, stream>>>(W_out, 2048, 2048, WoutT_hi, WoutT_lo);
    transpose_cvt<<<dim3(64, 128), blk, 0, stream>>>(W_gc, 4096, 2048, WgcT, nullptr);
    transpose_cvt<<<dim3(32, 64), blk, 0, stream>>>(W_gate, 2048, 1024, WgateT, nullptr);

    // x_in = [x_re|x_im] @ W_mix + b_mix   (split precision)
    gemm_kernel<true, 0><<<dim3(16, 64), blk, 0, stream>>>(
        x_re, 1024, x_im, 1024, 1024, WmixT_hi, WmixT_lo, b_mix, x_in, 2048,
        M_ROWS, 2048, 2048);

    scan_phase1<<<dim3(1024), blk, 0, stream>>>(x_in, dt_seq, decay_re, decay_im, S);
    scan_phase2<<<dim3(16), blk, 0, stream>>>(S, h0_re, h0_im, Pre);
    scan_phase3<<<dim3(1024), blk, 0, stream>>>(x_in, dt_seq, decay_re, decay_im, Pre, state);

    // src = state_cat @ W_out + b_out  -> out[:, 0:2048]   (split precision)
    gemm_kernel<true, 0><<<dim3(16, 64), blk, 0, stream>>>(
        state, 2048, state, 2048, 2048, WoutT_hi, WoutT_lo, b_out, out, 3072,
        M_ROWS, 2048, 2048);

    // gate_ctx = [state_cat | src] @ W_gc + b_gc  (plain bf16), gate_ctx aliases x_in
    gemm_kernel<false, 0><<<dim3(16, 64), blk, 0, stream>>>(
        state, 2048, out, 3072, 2048, WgcT, nullptr, b_gc, x_in, 2048,
        M_ROWS, 2048, 4096);

    // gate = sigmoid(gate_ctx @ W_gate + b_gate)*0.98+0.01 -> out[:, 2048:3072]
    gemm_kernel<false, 1><<<dim3(8, 64), blk, 0, stream>>>(
        x_in, 2048, x_in, 2048, 2048, WgateT, nullptr, b_gate, out + 2048, 3072,
        M_ROWS, 1024, 2048);
}

// Round 2
// 946.125 us; speedup vs baseline: 1.7700x; 1.7700x over previous
//
#include <hip/hip_runtime.h>

typedef __attribute__((ext_vector_type(8))) short short8;
typedef __attribute__((ext_vector_type(4))) float f32x4;
typedef unsigned short ushort_t;

#define T_SEQ 2048
#define D_DIM 1024
#define M_ROWS 8192
#define CT 32
#define NC (T_SEQ / CT)

__device__ __forceinline__ unsigned short f2bf_rne(float v) {
    unsigned int u = __float_as_uint(v);
    unsigned int r = (u + 0x7fffu + ((u >> 16) & 1u)) >> 16;
    return (unsigned short)r;
}
__device__ __forceinline__ float bf2f(unsigned short u) {
    return __uint_as_float(((unsigned int)u) << 16);
}
// stored column for logical element (m,k): XOR-swizzle 8-elem quarters within 32-k tiles
__device__ __forceinline__ int swz_col(int m, int k) {
    return (k & ~31) | ((((k >> 3) ^ (m >> 1)) & 3) << 3) | (k & 7);
}

__device__ __forceinline__ void gld16(const ushort_t* g, ushort_t* l) {
    __builtin_amdgcn_global_load_lds(
        (const __attribute__((address_space(1))) unsigned int*)g,
        (__attribute__((address_space(3))) unsigned int*)l, 16, 0, 0);
}

// ---------------- converters ----------------
// x_re,x_im (each M x 1024 f32) -> xcat hi/lo (M x 2048 bf16, swizzled)
__global__ void cvt_x(const float* __restrict__ xre, const float* __restrict__ xim,
                      ushort_t* __restrict__ hi, ushort_t* __restrict__ lo) {
    int g = blockIdx.x * 256 + threadIdx.x;
    int m = g >> 8, cidx = g & 255;
    int q = (cidx ^ (m >> 1)) & 3;
    int korig = ((cidx >> 2) << 5) + (q << 3);
    const float* src = (korig < 1024) ? (xre + (long)m * 1024 + korig)
                                      : (xim + (long)m * 1024 + korig - 1024);
    float4 v0 = *(const float4*)src;
    float4 v1 = *(const float4*)(src + 4);
    float vv[8] = {v0.x, v0.y, v0.z, v0.w, v1.x, v1.y, v1.z, v1.w};
    union { short8 v; ushort_t u[8]; } H, L;
#pragma unroll
    for (int j = 0; j < 8; j++) {
        ushort_t h = f2bf_rne(vv[j]);
        H.u[j] = h;
        L.u[j] = f2bf_rne(vv[j] - bf2f(h));
    }
    long o = (long)m * 2048 + cidx * 8;
    *(short8*)&hi[o] = H.v;
    *(short8*)&lo[o] = L.v;
}

// src (M x K f32 row-major) -> hi(/lo) (M x K bf16, swizzled rows)
__global__ void cvt_rows(const float* __restrict__ src, ushort_t* __restrict__ hi,
                         ushort_t* __restrict__ lo, int K) {
    int cpr = K >> 3;
    int g = blockIdx.x * 256 + threadIdx.x;
    int m = g / cpr, cidx = g % cpr;
    int q = (cidx ^ (m >> 1)) & 3;
    int korig = ((cidx >> 2) << 5) + (q << 3);
    const float* p = src + (long)m * K + korig;
    float4 v0 = *(const float4*)p;
    float4 v1 = *(const float4*)(p + 4);
    float vv[8] = {v0.x, v0.y, v0.z, v0.w, v1.x, v1.y, v1.z, v1.w};
    union { short8 v; ushort_t u[8]; } H, L;
#pragma unroll
    for (int j = 0; j < 8; j++) {
        ushort_t h = f2bf_rne(vv[j]);
        H.u[j] = h;
        L.u[j] = lo ? f2bf_rne(vv[j] - bf2f(h)) : 0;
    }
    long o = (long)m * K + cidx * 8;
    *(short8*)&hi[o] = H.v;
    if (lo) *(short8*)&lo[o] = L.v;
}

// W (K x N f32) -> WT (N x K bf16, swizzled rows)
__global__ void transpose_cvt_swz(const float* __restrict__ W, int K, int N,
                                  ushort_t* __restrict__ hi, ushort_t* __restrict__ lo) {
    __shared__ float tile[32][33];
    int kt = blockIdx.y * 32, nt = blockIdx.x * 32;
    int c = threadIdx.x & 31, r0 = threadIdx.x >> 5;
#pragma unroll
    for (int i = 0; i < 4; i++)
        tile[r0 + i * 8][c] = W[(long)(kt + r0 + i * 8) * N + nt + c];
    __syncthreads();
#pragma unroll
    for (int i = 0; i < 4; i++) {
        int n = r0 + i * 8;
        int m = nt + n;
        float v = tile[c][n];  // = W[kt+c][m]
        int q = ((c >> 3) ^ (m >> 1)) & 3;
        long o = (long)m * K + kt + (q << 3) + (c & 7);
        ushort_t h = f2bf_rne(v);
        hi[o] = h;
        if (lo) lo[o] = f2bf_rne(v - bf2f(h));
    }
}

// outv[n] = badd[n] + sum_k v[k]*W[k*N+n]
__global__ void gemv_fold(const float* __restrict__ v, const float* __restrict__ W,
                          const float* __restrict__ badd, float* __restrict__ outv,
                          int K, int N) {
    __shared__ float red[256];
    int nl = threadIdx.x & 63, kp = threadIdx.x >> 6;
    int n = blockIdx.x * 64 + nl;
    float s = 0.f;
    for (int k = kp; k < K; k += 4) s += v[k] * W[(long)k * N + n];
    red[threadIdx.x] = s;
    __syncthreads();
    if (kp == 0)
        outv[n] = red[nl] + red[nl + 64] + red[nl + 128] + red[nl + 192] + badd[n];
}

// ---------------- GEMM: C = A @ B^T(+Cadd)(+bias)(act), pre-swizzled bf16 operands ----------------
template <bool SPLIT, int ACT, bool ADDM>
__global__ __launch_bounds__(256, 2) void gemm_bf16(
    const ushort_t* __restrict__ Ahi, const ushort_t* __restrict__ Alo,
    const ushort_t* __restrict__ Bhi, const ushort_t* __restrict__ Blo,
    const float* __restrict__ bias,
    const float* __restrict__ Cadd, int ldadd,
    float* __restrict__ C, long ldc, int K) {
    constexpr int NS = SPLIT ? 4 : 2;
    __shared__ ushort_t lds[2][NS][128 * 32];

    const int tid = threadIdx.x;
    const int lane = tid & 63;
    const int wave = tid >> 6;
    const int wr = wave >> 1, wc = wave & 1;
    const int lr = lane & 15, kc = lane >> 4;
    const int row0 = blockIdx.y * 128, col0 = blockIdx.x * 128;
    const int sr = tid >> 2, sq = tid & 3;

    f32x4 acc[4][4] = {};

    auto stage = [&](int buf, int kt) {
        const long kbase = (long)kt * 32 + sq * 8;
#pragma unroll
        for (int j = 0; j < 2; j++) {
            gld16(Ahi + (long)(row0 + j * 64 + sr) * K + kbase, &lds[buf][0][(j * 256 + tid) * 8]);
            if constexpr (SPLIT)
                gld16(Alo + (long)(row0 + j * 64 + sr) * K + kbase, &lds[buf][1][(j * 256 + tid) * 8]);
        }
#pragma unroll
        for (int j = 0; j < 2; j++) {
            gld16(Bhi + (long)(col0 + j * 64 + sr) * K + kbase, &lds[buf][SPLIT ? 2 : 1][(j * 256 + tid) * 8]);
            if constexpr (SPLIT)
                gld16(Blo + (long)(col0 + j * 64 + sr) * K + kbase, &lds[buf][3][(j * 256 + tid) * 8]);
        }
    };

    const int nkt = K >> 5;
    stage(0, 0);
    __syncthreads();
    int cur = 0;
    for (int kt = 0; kt < nkt; kt++) {
        if (kt + 1 < nkt) stage(cur ^ 1, kt + 1);

        const ushort_t* sAh = lds[cur][0];
        const ushort_t* sBh = lds[cur][SPLIT ? 2 : 1];
        short8 ahi[4], bhi[4], alo[4], blo[4];
#pragma unroll
        for (int mi = 0; mi < 4; mi++) {
            int r = wr * 64 + mi * 16 + lr;
            int idx = (r * 32 + kc * 8) ^ (((r >> 1) & 3) << 3);
            ahi[mi] = *(const short8*)&sAh[idx];
            if constexpr (SPLIT) alo[mi] = *(const short8*)&lds[cur][1][idx];
        }
#pragma unroll
        for (int ni = 0; ni < 4; ni++) {
            int r = wc * 64 + ni * 16 + lr;
            int idx = (r * 32 + kc * 8) ^ (((r >> 1) & 3) << 3);
            bhi[ni] = *(const short8*)&sBh[idx];
            if constexpr (SPLIT) blo[ni] = *(const short8*)&lds[cur][3][idx];
        }
#pragma unroll
        for (int mi = 0; mi < 4; mi++)
#pragma unroll
            for (int ni = 0; ni < 4; ni++)
                acc[mi][ni] = __builtin_amdgcn_mfma_f32_16x16x32_bf16(ahi[mi], bhi[ni], acc[mi][ni], 0, 0, 0);
        if constexpr (SPLIT) {
#pragma unroll
            for (int mi = 0; mi < 4; mi++)
#pragma unroll
                for (int ni = 0; ni < 4; ni++)
                    acc[mi][ni] = __builtin_amdgcn_mfma_f32_16x16x32_bf16(ahi[mi], blo[ni], acc[mi][ni], 0, 0, 0);
#pragma unroll
            for (int mi = 0; mi < 4; mi++)
#pragma unroll
                for (int ni = 0; ni < 4; ni++)
                    acc[mi][ni] = __builtin_amdgcn_mfma_f32_16x16x32_bf16(alo[mi], bhi[ni], acc[mi][ni], 0, 0, 0);
        }
        __syncthreads();
        cur ^= 1;
    }

    float bv[4];
#pragma unroll
    for (int ni = 0; ni < 4; ni++) bv[ni] = bias ? bias[col0 + wc * 64 + ni * 16 + lr] : 0.f;
#pragma unroll
    for (int mi = 0; mi < 4; mi++) {
        int rbase = row0 + wr * 64 + mi * 16 + kc * 4;
#pragma unroll
        for (int ni = 0; ni < 4; ni++) {
            int c = col0 + wc * 64 + ni * 16 + lr;
#pragma unroll
            for (int i = 0; i < 4; i++) {
                float v = acc[mi][ni][i] + bv[ni];
                if constexpr (ADDM) v += Cadd[(long)(rbase + i) * ldadd + c];
                if constexpr (ACT == 1) v = 0.98f / (1.0f + expf(-v)) + 0.01f;
                C[(long)(rbase + i) * ldc + c] = v;
            }
        }
    }
}

// ---------------- scan ----------------
__device__ __forceinline__ void step_coefs(float lre, float lim, float dt,
                                           float& are, float& aim,
                                           float& fre, float& fim) {
    float zr = lre * dt, zi = lim * dt;
    float er = expm1f(zr);
    float ex = er + 1.0f;
    float cy = cosf(zi), sy = sinf(zi);
    float sh = sinf(0.5f * zi);
    are = ex * cy;
    aim = ex * sy;
    float nr = er * cy - 2.0f * sh * sh;
    float ni = ex * sy;
    float r2 = zr * zr + zi * zi;
    float pr, pi;
    if (r2 > 1e-14f) {
        float inv = 1.0f / r2;
        pr = (nr * zr + ni * zi) * inv;
        pi = (ni * zr - nr * zi) * inv;
    } else {
        pr = 1.0f + 0.5f * zr + (zr * zr - zi * zi) * (1.0f / 6.0f);
        pi = 0.5f * zi + (zr * zi) * (1.0f / 3.0f);
    }
    fre = dt * pr;
    fim = dt * pi;
}

__device__ __forceinline__ void lam_of(const float* dre, const float* dim, int d,
                                       float& lre, float& lim) {
    float x = dre[d];
    float sp = fmaxf(x, 0.0f) + log1pf(expf(-fabsf(x)));
    lre = -sp;
    lim = dim[d];
}

__global__ void scan_phase1(const float* __restrict__ x_in,
                            const float* __restrict__ dt_seq,
                            const float* __restrict__ decay_re,
                            const float* __restrict__ decay_im,
                            float4* __restrict__ S) {
    int gw = (blockIdx.x * blockDim.x + threadIdx.x) >> 6;
    int lane = threadIdx.x & 63;
    int d64 = gw & 15;
    int c = (gw >> 4) & (NC - 1);
    int b = gw >> 10;
    int d = d64 * 64 + lane;
    float lre, lim;
    lam_of(decay_re, decay_im, d, lre, lim);
    float Are = 1.f, Aim = 0.f, Bre = 0.f, Bim = 0.f;
    for (int j = 0; j < CT; j++) {
        int t = c * CT + j;
        float dt = dt_seq[b * T_SEQ + t];
        float are, aim, fre, fim;
        step_coefs(lre, lim, dt, are, aim, fre, fim);
        size_t off = ((size_t)(b * T_SEQ + t)) * 2048;
        float xr = x_in[off + d];
        float xi = x_in[off + 1024 + d];
        float xsr = xr * fre - xi * fim;
        float xsi = xr * fim + xi * fre;
        float nbr = are * Bre - aim * Bim + xsr;
        float nbi = are * Bim + aim * Bre + xsi;
        Bre = nbr; Bim = nbi;
        float nar = are * Are - aim * Aim;
        float nai = are * Aim + aim * Are;
        Are = nar; Aim = nai;
    }
    S[(size_t)(b * NC + c) * D_DIM + d] = make_float4(Are, Aim, Bre, Bim);
}

__global__ void scan_phase2(const float4* __restrict__ S,
                            const float* __restrict__ h0_re,
                            const float* __restrict__ h0_im,
                            float2* __restrict__ Pre) {
    int idx = blockIdx.x * blockDim.x + threadIdx.x;
    int b = idx >> 10, d = idx & 1023;
    float Are = 1.f, Aim = 0.f;
    float Bre = h0_re[d], Bim = h0_im[d];
    for (int c = 0; c < NC; c++) {
        Pre[(size_t)(b * NC + c) * D_DIM + d] = make_float2(Bre, Bim);
        float4 s = S[(size_t)(b * NC + c) * D_DIM + d];
        float nAre = s.x * Are - s.y * Aim;
        float nAim = s.x * Aim + s.y * Are;
        float nBre = s.x * Bre - s.y * Bim + s.z;
        float nBim = s.x * Bim + s.y * Bre + s.w;
        Are = nAre; Aim = nAim; Bre = nBre; Bim = nBim;
    }
}

// phase 3: writes state directly as swizzled bf16 hi/lo (A-operand layout)
__global__ void scan_phase3(const float* __restrict__ x_in,
                            const float* __restrict__ dt_seq,
                            const float* __restrict__ decay_re,
                            const float* __restrict__ decay_im,
                            const float2* __restrict__ Pre,
                            ushort_t* __restrict__ sthi,
                            ushort_t* __restrict__ stlo) {
    int gw = (blockIdx.x * blockDim.x + threadIdx.x) >> 6;
    int lane = threadIdx.x & 63;
    int d64 = gw & 15;
    int c = (gw >> 4) & (NC - 1);
    int b = gw >> 10;
    int d = d64 * 64 + lane;
    float lre, lim;
    lam_of(decay_re, decay_im, d, lre, lim);
    float2 h = Pre[(size_t)(b * NC + c) * D_DIM + d];
    float hre = h.x, him = h.y;
    for (int j = 0; j < CT; j++) {
        int t = c * CT + j;
        int m = b * T_SEQ + t;
        float dt = dt_seq[m];
        float are, aim, fre, fim;
        step_coefs(lre, lim, dt, are, aim, fre, fim);
        size_t off = ((size_t)m) * 2048;
        float xr = x_in[off + d];
        float xi = x_in[off + 1024 + d];
        float xsr = xr * fre - xi * fim;
        float xsi = xr * fim + xi * fre;
        float nre = are * hre - aim * him + xsr;
        float nim = are * him + aim * hre + xsi;
        hre = nre; him = nim;
        long idx = (long)m * 2048 + swz_col(m, d);
        ushort_t hr = f2bf_rne(hre);
        ushort_t hi2 = f2bf_rne(him);
        sthi[idx] = hr;
        sthi[idx + 1024] = hi2;
        stlo[idx] = f2bf_rne(hre - bf2f(hr));
        stlo[idx + 1024] = f2bf_rne(him - bf2f(hi2));
    }
}

extern "C" void kernel_launch(void* const* d_in, const int* in_sizes, int n_in,
                              void* d_out, int out_size, void* d_ws, size_t ws_size,
                              hipStream_t stream) {
    const float* x_re = (const float*)d_in[0];
    const float* x_im = (const float*)d_in[1];
    const float* dt_seq = (const float*)d_in[2];
    const float* decay_re = (const float*)d_in[3];
    const float* decay_im = (const float*)d_in[4];
    const float* h0_re = (const float*)d_in[5];
    const float* h0_im = (const float*)d_in[6];
    const float* W_mix = (const float*)d_in[7];
    const float* b_mix = (const float*)d_in[8];
    const float* W_out = (const float*)d_in[9];
    const float* b_out = (const float*)d_in[10];
    const float* W_gc = (const float*)d_in[11];
    const float* b_gc = (const float*)d_in[12];
    const float* W_gate = (const float*)d_in[13];
    const float* b_gate = (const float*)d_in[14];
    float* out = (float*)d_out;

    char* ws = (char*)d_ws;
    const unsigned long MB = 1048576ull;
    // Region A: x_in (64 MB)
    float* x_in = (float*)(ws);
    // Region B (64 MB): precompute transients, then xcat, then state (aliased in time)
    char* B = ws + 64 * MB;
    ushort_t* xcat_hi = (ushort_t*)B;            // 32 MB
    ushort_t* xcat_lo = (ushort_t*)(B + 32 * MB);
    ushort_t* state_hi = (ushort_t*)B;           // aliases xcat (xcat dead after G1)
    ushort_t* state_lo = (ushort_t*)(B + 32 * MB);
    // transients (dead before cvt_x):
    ushort_t* WgcbT = (ushort_t*)B;                         // 8 MB
    ushort_t* WgateT = (ushort_t*)(B + 8 * MB);             // 4 MB
    ushort_t* Wout_rows = (ushort_t*)(B + 12 * MB);         // 8 MB
    float* tmp1 = (float*)(B + 20 * MB);                    // 16 MB
    ushort_t* tmp1_hi = (ushort_t*)(B + 36 * MB);           // 8 MB
    float* W_total = (float*)(B + 44 * MB);                 // 8 MB
    // Region C (persistent per launch)
    char* Cr = ws + 128 * MB;
    float4* S = (float4*)Cr;                                // 4 MB
    float2* Pre = (float2*)(Cr + 4 * MB);                   // 2 MB
    ushort_t* WmixT_hi = (ushort_t*)(Cr + 6 * MB);          // 8 MB
    ushort_t* WmixT_lo = (ushort_t*)(Cr + 14 * MB);         // 8 MB
    ushort_t* WoutT_hi = (ushort_t*)(Cr + 22 * MB);         // 8 MB
    ushort_t* WoutT_lo = (ushort_t*)(Cr + 30 * MB);         // 8 MB
    ushort_t* WtotT_hi = (ushort_t*)(Cr + 38 * MB);         // 4 MB
    float* b_eff = (float*)(Cr + 42 * MB);                  // 8 KB
    float* b_total = (float*)(Cr + 42 * MB + 65536);        // 4 KB

    dim3 blk(256);

    // ---- weight precompute ----
    transpose_cvt_swz<<<dim3(64, 64), blk, 0, stream>>>(W_mix, 2048, 2048, WmixT_hi, WmixT_lo);
    transpose_cvt_swz<<<dim3(64, 64), blk, 0, stream>>>(W_out, 2048, 2048, WoutT_hi, WoutT_lo);
    transpose_cvt_swz<<<dim3(64, 64), blk, 0, stream>>>(W_gc + 2048 * 2048, 2048, 2048, WgcbT, nullptr);
    transpose_cvt_swz<<<dim3(32, 64), blk, 0, stream>>>(W_gate, 2048, 1024, WgateT, nullptr);
    cvt_rows<<<dim3(2048), blk, 0, stream>>>(W_out, Wout_rows, nullptr, 2048);
    gemv_fold<<<dim3(32), blk, 0, stream>>>(b_out, W_gc + 2048 * 2048, b_gc, b_eff, 2048, 2048);
    // tmp1 = W_out @ W_gc_bot + W_gc_top
    gemm_bf16<false, 0, true><<<dim3(16, 16), blk, 0, stream>>>(
        Wout_rows, nullptr, WgcbT, nullptr, nullptr, W_gc, 2048, tmp1, 2048, 2048);
    cvt_rows<<<dim3(2048), blk, 0, stream>>>(tmp1, tmp1_hi, nullptr, 2048);
    // W_total = tmp1 @ W_gate
    gemm_bf16<false, 0, false><<<dim3(8, 16), blk, 0, stream>>>(
        tmp1_hi, nullptr, WgateT, nullptr, nullptr, nullptr, 0, W_total, 1024, 2048);
    transpose_cvt_swz<<<dim3(32, 64), blk, 0, stream>>>(W_total, 2048, 1024, WtotT_hi, nullptr);
    gemv_fold<<<dim3(16), blk, 0, stream>>>(b_eff, W_gate, b_gate, b_total, 2048, 1024);

    // ---- x conversion + mix GEMM ----
    cvt_x<<<dim3(8192), blk, 0, stream>>>(x_re, x_im, xcat_hi, xcat_lo);
    gemm_bf16<true, 0, false><<<dim3(16, 64), blk, 0, stream>>>(
        xcat_hi, xcat_lo, WmixT_hi, WmixT_lo, b_mix, nullptr, 0, x_in, 2048, 2048);

    // ---- scan ----
    scan_phase1<<<dim3(1024), blk, 0, stream>>>(x_in, dt_seq, decay_re, decay_im, S);
    scan_phase2<<<dim3(16), blk, 0, stream>>>(S, h0_re, h0_im, Pre);
    scan_phase3<<<dim3(1024), blk, 0, stream>>>(x_in, dt_seq, decay_re, decay_im, Pre,
                                                state_hi, state_lo);

    // ---- src = state @ W_out + b_out -> out[:, 0:2048] ----
    gemm_bf16<true, 0, false><<<dim3(16, 64), blk, 0, stream>>>(
        state_hi, state_lo, WoutT_hi, WoutT_lo, b_out, nullptr, 0, out, 3072, 2048);

    // ---- gate = sigmoid(state @ W_total + b_total)*0.98+0.01 -> out[:, 2048:3072] ----
    gemm_bf16<false, 1, false><<<dim3(8, 64), blk, 0, stream>>>(
        state_hi, nullptr, WtotT_hi, nullptr, b_total, nullptr, 0, out + 2048, 3072, 2048);
}

// Round 3
// 666.480 us; speedup vs baseline: 2.5126x; 1.4196x over previous
//
#include <hip/hip_runtime.h>

typedef __attribute__((ext_vector_type(8))) short short8;
typedef __attribute__((ext_vector_type(4))) float f32x4;
typedef unsigned short ushort_t;

#define T_SEQ 2048
#define D_DIM 1024
#define M_ROWS 8192
#define CT 32
#define NC (T_SEQ / CT)

__device__ __forceinline__ unsigned short f2bf_rne(float v) {
    unsigned int u = __float_as_uint(v);
    unsigned int r = (u + 0x7fffu + ((u >> 16) & 1u)) >> 16;
    return (unsigned short)r;
}
__device__ __forceinline__ float bf2f(unsigned short u) {
    return __uint_as_float(((unsigned int)u) << 16);
}
__device__ __forceinline__ int swz_col(int m, int k) {
    return (k & ~31) | ((((k >> 3) ^ (m >> 1)) & 3) << 3) | (k & 7);
}

__device__ __forceinline__ void gld16(const ushort_t* g, ushort_t* l) {
    __builtin_amdgcn_global_load_lds(
        (const __attribute__((address_space(1))) unsigned int*)g,
        (__attribute__((address_space(3))) unsigned int*)l, 16, 0, 0);
}

// ---------------- converters ----------------
__global__ void cvt_x(const float* __restrict__ xre, const float* __restrict__ xim,
                      ushort_t* __restrict__ hi, ushort_t* __restrict__ lo) {
    int g = blockIdx.x * 256 + threadIdx.x;
    int m = g >> 8, cidx = g & 255;
    int q = (cidx ^ (m >> 1)) & 3;
    int korig = ((cidx >> 2) << 5) + (q << 3);
    const float* src = (korig < 1024) ? (xre + (long)m * 1024 + korig)
                                      : (xim + (long)m * 1024 + korig - 1024);
    float4 v0 = *(const float4*)src;
    float4 v1 = *(const float4*)(src + 4);
    float vv[8] = {v0.x, v0.y, v0.z, v0.w, v1.x, v1.y, v1.z, v1.w};
    union { short8 v; ushort_t u[8]; } H, L;
#pragma unroll
    for (int j = 0; j < 8; j++) {
        ushort_t h = f2bf_rne(vv[j]);
        H.u[j] = h;
        L.u[j] = f2bf_rne(vv[j] - bf2f(h));
    }
    long o = (long)m * 2048 + cidx * 8;
    *(short8*)&hi[o] = H.v;
    *(short8*)&lo[o] = L.v;
}

__global__ void cvt_rows(const float* __restrict__ src, ushort_t* __restrict__ hi, int K) {
    int cpr = K >> 3;
    int g = blockIdx.x * 256 + threadIdx.x;
    int m = g / cpr, cidx = g % cpr;
    int q = (cidx ^ (m >> 1)) & 3;
    int korig = ((cidx >> 2) << 5) + (q << 3);
    const float* p = src + (long)m * K + korig;
    float4 v0 = *(const float4*)p;
    float4 v1 = *(const float4*)(p + 4);
    float vv[8] = {v0.x, v0.y, v0.z, v0.w, v1.x, v1.y, v1.z, v1.w};
    union { short8 v; ushort_t u[8]; } H;
#pragma unroll
    for (int j = 0; j < 8; j++) H.u[j] = f2bf_rne(vv[j]);
    *(short8*)&hi[(long)m * K + cidx * 8] = H.v;
}

// W (K x N f32) -> WT (N x K bf16, swizzled rows)
__global__ void transpose_cvt_swz(const float* __restrict__ W, int K, int N,
                                  ushort_t* __restrict__ hi) {
    __shared__ float tile[32][33];
    int kt = blockIdx.y * 32, nt = blockIdx.x * 32;
    int c = threadIdx.x & 31, r0 = threadIdx.x >> 5;
#pragma unroll
    for (int i = 0; i < 4; i++)
        tile[r0 + i * 8][c] = W[(long)(kt + r0 + i * 8) * N + nt + c];
    __syncthreads();
#pragma unroll
    for (int i = 0; i < 4; i++) {
        int n = r0 + i * 8;
        int m = nt + n;
        float v = tile[c][n];
        int q = ((c >> 3) ^ (m >> 1)) & 3;
        hi[(long)m * K + kt + (q << 3) + (c & 7)] = f2bf_rne(v);
    }
}

// ---------------- small gemv (k-sliced) ----------------
__global__ void gemv_part(const float* __restrict__ v, const float* __restrict__ W,
                          float* __restrict__ part, int K, int N) {
    int n = blockIdx.x * 256 + threadIdx.x;
    int slice = blockIdx.y;
    int kn = K >> 3;
    int k0 = slice * kn;
    float s = 0.f;
    for (int k = k0; k < k0 + kn; k++) s += v[k] * W[(long)k * N + n];
    part[(long)slice * N + n] = s;
}
__global__ void reduce_vec(const float* __restrict__ part, const float* __restrict__ badd,
                           float* __restrict__ outv, int N) {
    int n = blockIdx.x * 256 + threadIdx.x;
    float s = badd[n];
#pragma unroll
    for (int i = 0; i < 8; i++) s += part[(long)i * N + n];
    outv[n] = s;
}
__global__ void copy_vec(const float* __restrict__ src, float* __restrict__ dst) {
    int n = blockIdx.x * 256 + threadIdx.x;
    dst[n] = src[n];
}

// ---------------- GEMM: C = A @ B^T (+Cadd)(+bias)(act) ----------------
// SPLIT: A given as hi+lo (2 MFMA terms: ahi*bhi + alo*bhi). B always hi only.
// ACT==2: sigmoid-gate for blocks with col0 >= 2048.
template <bool SPLIT, int ACT, bool ADDM>
__global__ __launch_bounds__(256, 3) void gemm_bf16(
    const ushort_t* __restrict__ Ahi, const ushort_t* __restrict__ Alo,
    const ushort_t* __restrict__ Bhi,
    const float* __restrict__ bias,
    const float* __restrict__ Cadd, int ldadd,
    float* __restrict__ C, long ldc, int K) {
    constexpr int NS = SPLIT ? 3 : 2;
    __shared__ ushort_t lds[2][NS][128 * 32];

    const int tid = threadIdx.x;
    const int lane = tid & 63;
    const int wave = tid >> 6;
    const int wr = wave >> 1, wc = wave & 1;
    const int lr = lane & 15, kc = lane >> 4;
    const int row0 = blockIdx.y * 128, col0 = blockIdx.x * 128;
    const int sr = tid >> 2, sq = tid & 3;

    f32x4 acc[4][4] = {};

    auto stage = [&](int buf, int kt) {
        const long kbase = (long)kt * 32 + sq * 8;
#pragma unroll
        for (int j = 0; j < 2; j++) {
            gld16(Ahi + (long)(row0 + j * 64 + sr) * K + kbase, &lds[buf][0][(j * 256 + tid) * 8]);
            if constexpr (SPLIT)
                gld16(Alo + (long)(row0 + j * 64 + sr) * K + kbase, &lds[buf][1][(j * 256 + tid) * 8]);
        }
#pragma unroll
        for (int j = 0; j < 2; j++)
            gld16(Bhi + (long)(col0 + j * 64 + sr) * K + kbase, &lds[buf][NS - 1][(j * 256 + tid) * 8]);
    };

    const int nkt = K >> 5;
    stage(0, 0);
    __syncthreads();
    int cur = 0;
    for (int kt = 0; kt < nkt; kt++) {
        if (kt + 1 < nkt) stage(cur ^ 1, kt + 1);

        short8 ahi[4], bhi[4], alo[4];
#pragma unroll
        for (int mi = 0; mi < 4; mi++) {
            int r = wr * 64 + mi * 16 + lr;
            int idx = (r * 32 + kc * 8) ^ (((r >> 1) & 3) << 3);
            ahi[mi] = *(const short8*)&lds[cur][0][idx];
            if constexpr (SPLIT) alo[mi] = *(const short8*)&lds[cur][1][idx];
        }
#pragma unroll
        for (int ni = 0; ni < 4; ni++) {
            int r = wc * 64 + ni * 16 + lr;
            int idx = (r * 32 + kc * 8) ^ (((r >> 1) & 3) << 3);
            bhi[ni] = *(const short8*)&lds[cur][NS - 1][idx];
        }
#pragma unroll
        for (int mi = 0; mi < 4; mi++)
#pragma unroll
            for (int ni = 0; ni < 4; ni++)
                acc[mi][ni] = __builtin_amdgcn_mfma_f32_16x16x32_bf16(ahi[mi], bhi[ni], acc[mi][ni], 0, 0, 0);
        if constexpr (SPLIT) {
#pragma unroll
            for (int mi = 0; mi < 4; mi++)
#pragma unroll
                for (int ni = 0; ni < 4; ni++)
                    acc[mi][ni] = __builtin_amdgcn_mfma_f32_16x16x32_bf16(alo[mi], bhi[ni], acc[mi][ni], 0, 0, 0);
        }
        __syncthreads();
        cur ^= 1;
    }

    const bool gate_blk = (ACT == 2) && (col0 >= 2048);
    float bv[4];
#pragma unroll
    for (int ni = 0; ni < 4; ni++) bv[ni] = bias ? bias[col0 + wc * 64 + ni * 16 + lr] : 0.f;
#pragma unroll
    for (int mi = 0; mi < 4; mi++) {
        int rbase = row0 + wr * 64 + mi * 16 + kc * 4;
#pragma unroll
        for (int ni = 0; ni < 4; ni++) {
            int c = col0 + wc * 64 + ni * 16 + lr;
#pragma unroll
            for (int i = 0; i < 4; i++) {
                float v = acc[mi][ni][i] + bv[ni];
                if constexpr (ADDM) v += Cadd[(long)(rbase + i) * ldadd + c];
                if constexpr (ACT == 2) {
                    if (gate_blk) v = 0.98f / (1.0f + expf(-v)) + 0.01f;
                }
                C[(long)(rbase + i) * ldc + c] = v;
            }
        }
    }
}

// ---------------- scan ----------------
__device__ __forceinline__ void step_coefs(float lre, float lim, float dt,
                                           float& are, float& aim,
                                           float& fre, float& fim) {
    float zr = lre * dt, zi = lim * dt;
    float ex = __expf(zr);
    float er = ex - 1.0f;
    float hh = 0.5f * zi;
    float s = __sinf(hh), c = __cosf(hh);
    float s2s = 2.0f * s * s;      // 1 - cos(zi)
    float cy = 1.0f - s2s;
    float sy = 2.0f * s * c;
    are = ex * cy;
    aim = ex * sy;
    float nr = er * cy - s2s;
    float ni = ex * sy;
    float r2 = zr * zr + zi * zi;
    float pr, pi;
    if (r2 > 1e-14f) {
        float inv = 1.0f / r2;
        pr = (nr * zr + ni * zi) * inv;
        pi = (ni * zr - nr * zi) * inv;
    } else {
        pr = 1.0f + 0.5f * zr;
        pi = 0.5f * zi;
    }
    fre = dt * pr;
    fim = dt * pi;
}

__device__ __forceinline__ void lam_of(const float* dre, const float* dim, int d,
                                       float& lre, float& lim) {
    float x = dre[d];
    float sp = fmaxf(x, 0.0f) + log1pf(expf(-fabsf(x)));
    lre = -sp;
    lim = dim[d];
}

__global__ void scan_phase1(const float* __restrict__ x_in,
                            const float* __restrict__ dt_seq,
                            const float* __restrict__ decay_re,
                            const float* __restrict__ decay_im,
                            float4* __restrict__ S) {
    int gw = (blockIdx.x * blockDim.x + threadIdx.x) >> 6;
    int lane = threadIdx.x & 63;
    int d64 = gw & 15;
    int c = (gw >> 4) & (NC - 1);
    int b = gw >> 10;
    int d = d64 * 64 + lane;
    float lre, lim;
    lam_of(decay_re, decay_im, d, lre, lim);
    float Are = 1.f, Aim = 0.f, Bre = 0.f, Bim = 0.f;
    for (int j = 0; j < CT; j++) {
        int t = c * CT + j;
        float dt = dt_seq[b * T_SEQ + t];
        float are, aim, fre, fim;
        step_coefs(lre, lim, dt, are, aim, fre, fim);
        size_t off = ((size_t)(b * T_SEQ + t)) * 2048;
        float xr = x_in[off + d];
        float xi = x_in[off + 1024 + d];
        float xsr = xr * fre - xi * fim;
        float xsi = xr * fim + xi * fre;
        float nbr = are * Bre - aim * Bim + xsr;
        float nbi = are * Bim + aim * Bre + xsi;
        Bre = nbr; Bim = nbi;
        float nar = are * Are - aim * Aim;
        float nai = are * Aim + aim * Are;
        Are = nar; Aim = nai;
    }
    S[(size_t)(b * NC + c) * D_DIM + d] = make_float4(Are, Aim, Bre, Bim);
}

__global__ void scan_phase2(const float4* __restrict__ S,
                            const float* __restrict__ h0_re,
                            const float* __restrict__ h0_im,
                            float2* __restrict__ Pre) {
    int idx = blockIdx.x * blockDim.x + threadIdx.x;
    int b = idx >> 10, d = idx & 1023;
    float Are = 1.f, Aim = 0.f;
    float Bre = h0_re[d], Bim = h0_im[d];
    for (int c = 0; c < NC; c++) {
        Pre[(size_t)(b * NC + c) * D_DIM + d] = make_float2(Bre, Bim);
        float4 s = S[(size_t)(b * NC + c) * D_DIM + d];
        float nAre = s.x * Are - s.y * Aim;
        float nAim = s.x * Aim + s.y * Are;
        float nBre = s.x * Bre - s.y * Bim + s.z;
        float nBim = s.x * Bim + s.y * Bre + s.w;
        Are = nAre; Aim = nAim; Bre = nBre; Bim = nBim;
    }
}

__global__ void scan_phase3(const float* __restrict__ x_in,
                            const float* __restrict__ dt_seq,
                            const float* __restrict__ decay_re,
                            const float* __restrict__ decay_im,
                            const float2* __restrict__ Pre,
                            ushort_t* __restrict__ sthi,
                            ushort_t* __restrict__ stlo) {
    int gw = (blockIdx.x * blockDim.x + threadIdx.x) >> 6;
    int lane = threadIdx.x & 63;
    int d64 = gw & 15;
    int c = (gw >> 4) & (NC - 1);
    int b = gw >> 10;
    int d = d64 * 64 + lane;
    float lre, lim;
    lam_of(decay_re, decay_im, d, lre, lim);
    float2 h = Pre[(size_t)(b * NC + c) * D_DIM + d];
    float hre = h.x, him = h.y;
    for (int j = 0; j < CT; j++) {
        int t = c * CT + j;
        int m = b * T_SEQ + t;
        float dt = dt_seq[m];
        float are, aim, fre, fim;
        step_coefs(lre, lim, dt, are, aim, fre, fim);
        size_t off = ((size_t)m) * 2048;
        float xr = x_in[off + d];
        float xi = x_in[off + 1024 + d];
        float xsr = xr * fre - xi * fim;
        float xsi = xr * fim + xi * fre;
        float nre = are * hre - aim * him + xsr;
        float nim = are * him + aim * hre + xsi;
        hre = nre; him = nim;
        long idx = (long)m * 2048 + swz_col(m, d);
        ushort_t hr = f2bf_rne(hre);
        ushort_t hi2 = f2bf_rne(him);
        sthi[idx] = hr;
        sthi[idx + 1024] = hi2;
        stlo[idx] = f2bf_rne(hre - bf2f(hr));
        stlo[idx + 1024] = f2bf_rne(him - bf2f(hi2));
    }
}

extern "C" void kernel_launch(void* const* d_in, const int* in_sizes, int n_in,
                              void* d_out, int out_size, void* d_ws, size_t ws_size,
                              hipStream_t stream) {
    const float* x_re = (const float*)d_in[0];
    const float* x_im = (const float*)d_in[1];
    const float* dt_seq = (const float*)d_in[2];
    const float* decay_re = (const float*)d_in[3];
    const float* decay_im = (const float*)d_in[4];
    const float* h0_re = (const float*)d_in[5];
    const float* h0_im = (const float*)d_in[6];
    const float* W_mix = (const float*)d_in[7];
    const float* b_mix = (const float*)d_in[8];
    const float* W_out = (const float*)d_in[9];
    const float* b_out = (const float*)d_in[10];
    const float* W_gc = (const float*)d_in[11];
    const float* b_gc = (const float*)d_in[12];
    const float* W_gate = (const float*)d_in[13];
    const float* b_gate = (const float*)d_in[14];
    float* out = (float*)d_out;

    char* ws = (char*)d_ws;
    const unsigned long MB = 1048576ull;
    // Region A: x_in (64 MB)
    float* x_in = (float*)(ws);
    // Region B (64 MB): precompute transients, then xcat, then state (time-aliased)
    char* B = ws + 64 * MB;
    ushort_t* xcat_hi = (ushort_t*)B;
    ushort_t* xcat_lo = (ushort_t*)(B + 32 * MB);
    ushort_t* state_hi = (ushort_t*)B;
    ushort_t* state_lo = (ushort_t*)(B + 32 * MB);
    ushort_t* WgcbT = (ushort_t*)B;                       // 8 MB
    ushort_t* WgateT = (ushort_t*)(B + 8 * MB);           // 4 MB
    ushort_t* Wout_rows = (ushort_t*)(B + 12 * MB);       // 8 MB
    float* tmp1 = (float*)(B + 20 * MB);                  // 16 MB
    ushort_t* tmp1_hi = (ushort_t*)(B + 36 * MB);         // 8 MB
    float* W_total = (float*)(B + 44 * MB);               // 8 MB
    float* partA = (float*)(B + 52 * MB);                 // 64 KB
    float* partB = (float*)(B + 53 * MB);                 // 32 KB
    // Region C (persistent per launch)
    char* Cr = ws + 128 * MB;
    float4* S = (float4*)Cr;                              // 4 MB
    float2* Pre = (float2*)(Cr + 4 * MB);                 // 2 MB
    ushort_t* WmixT_hi = (ushort_t*)(Cr + 6 * MB);        // 8 MB
    ushort_t* WcatT_hi = (ushort_t*)(Cr + 14 * MB);       // 12 MB (3072 x 2048)
    float* b_eff = (float*)(Cr + 26 * MB);                // 8 KB
    float* b_cat = (float*)(Cr + 26 * MB + 65536);        // 12 KB (3072)

    dim3 blk(256);

    // ---- weight precompute ----
    transpose_cvt_swz<<<dim3(64, 64), blk, 0, stream>>>(W_mix, 2048, 2048, WmixT_hi);
    transpose_cvt_swz<<<dim3(64, 64), blk, 0, stream>>>(W_out, 2048, 2048, WcatT_hi);
    transpose_cvt_swz<<<dim3(64, 64), blk, 0, stream>>>(W_gc + 2048 * 2048, 2048, 2048, WgcbT);
    transpose_cvt_swz<<<dim3(32, 64), blk, 0, stream>>>(W_gate, 2048, 1024, WgateT);
    cvt_rows<<<dim3(2048), blk, 0, stream>>>(W_out, Wout_rows, 2048);
    copy_vec<<<dim3(8), blk, 0, stream>>>(b_out, b_cat);

    // b_eff = b_out @ W_gc_bot + b_gc
    gemv_part<<<dim3(8, 8), blk, 0, stream>>>(b_out, W_gc + 2048 * 2048, partA, 2048, 2048);
    reduce_vec<<<dim3(8), blk, 0, stream>>>(partA, b_gc, b_eff, 2048);

    // tmp1 = W_out @ W_gc_bot + W_gc_top
    gemm_bf16<false, 0, true><<<dim3(16, 16), blk, 0, stream>>>(
        Wout_rows, nullptr, WgcbT, nullptr, W_gc, 2048, tmp1, 2048, 2048);
    cvt_rows<<<dim3(2048), blk, 0, stream>>>(tmp1, tmp1_hi, 2048);
    // W_total = tmp1 @ W_gate
    gemm_bf16<false, 0, false><<<dim3(8, 16), blk, 0, stream>>>(
        tmp1_hi, nullptr, WgateT, nullptr, nullptr, 0, W_total, 1024, 2048);
    transpose_cvt_swz<<<dim3(32, 64), blk, 0, stream>>>(W_total, 2048, 1024,
                                                        WcatT_hi + 2048ull * 2048ull);
    // b_total = b_eff @ W_gate + b_gate -> b_cat[2048:]
    gemv_part<<<dim3(4, 8), blk, 0, stream>>>(b_eff, W_gate, partB, 2048, 1024);
    reduce_vec<<<dim3(4), blk, 0, stream>>>(partB, b_gate, b_cat + 2048, 1024);

    // ---- x conversion + mix GEMM ----
    cvt_x<<<dim3(8192), blk, 0, stream>>>(x_re, x_im, xcat_hi, xcat_lo);
    gemm_bf16<true, 0, false><<<dim3(16, 64), blk, 0, stream>>>(
        xcat_hi, xcat_lo, WmixT_hi, b_mix, nullptr, 0, x_in, 2048, 2048);

    // ---- scan ----
    scan_phase1<<<dim3(1024), blk, 0, stream>>>(x_in, dt_seq, decay_re, decay_im, S);
    scan_phase2<<<dim3(16), blk, 0, stream>>>(S, h0_re, h0_im, Pre);
    scan_phase3<<<dim3(1024), blk, 0, stream>>>(x_in, dt_seq, decay_re, decay_im, Pre,
                                                state_hi, state_lo);

    // ---- fused: [src | gate] = state @ [W_out | W_total] + [b_out | b_total] ----
    gemm_bf16<true, 2, false><<<dim3(24, 64), blk, 0, stream>>>(
        state_hi, state_lo, WcatT_hi, b_cat, nullptr, 0, out, 3072, 2048);
}

// Round 4
// 623.910 us; speedup vs baseline: 2.6841x; 1.0682x over previous
//
#include <hip/hip_runtime.h>

typedef __attribute__((ext_vector_type(8))) short short8;
typedef __attribute__((ext_vector_type(4))) float f32x4;
typedef unsigned short ushort_t;

#define T_SEQ 2048
#define D_DIM 1024
#define M_ROWS 8192
#define CT 32
#define NC (T_SEQ / CT)

__device__ __forceinline__ unsigned short f2bf_rne(float v) {
    unsigned int u = __float_as_uint(v);
    unsigned int r = (u + 0x7fffu + ((u >> 16) & 1u)) >> 16;
    return (unsigned short)r;
}
__device__ __forceinline__ float bf2f(unsigned short u) {
    return __uint_as_float(((unsigned int)u) << 16);
}
__device__ __forceinline__ int swz_col(int m, int k) {
    return (k & ~31) | ((((k >> 3) ^ (m >> 1)) & 3) << 3) | (k & 7);
}

__device__ __forceinline__ void gld16(const ushort_t* g, ushort_t* l) {
    __builtin_amdgcn_global_load_lds(
        (const __attribute__((address_space(1))) unsigned int*)g,
        (__attribute__((address_space(3))) unsigned int*)l, 16, 0, 0);
}

// ---------------- prep_all: all transposes + cvt_x + cvt_rows + bias init ----------------
__device__ __forceinline__ void transpose_job(const float* __restrict__ W, int K, int N,
                                              ushort_t* __restrict__ hi, int bx, int by,
                                              int tid, float (*tile)[33]) {
    int kt = by * 32, nt = bx * 32;
    int c = tid & 31, r0 = tid >> 5;
#pragma unroll
    for (int i = 0; i < 4; i++)
        tile[r0 + i * 8][c] = W[(long)(kt + r0 + i * 8) * N + nt + c];
    __syncthreads();
#pragma unroll
    for (int i = 0; i < 4; i++) {
        int n = r0 + i * 8;
        int m = nt + n;
        float v = tile[c][n];
        int q = ((c >> 3) ^ (m >> 1)) & 3;
        hi[(long)m * K + kt + (q << 3) + (c & 7)] = f2bf_rne(v);
    }
}

__global__ void prep_all(const float* __restrict__ W_mix, const float* __restrict__ W_out,
                         const float* __restrict__ W_gc, const float* __restrict__ W_gate,
                         const float* __restrict__ x_re, const float* __restrict__ x_im,
                         const float* __restrict__ b_out, const float* __restrict__ b_gate,
                         const float* __restrict__ b_gc,
                         ushort_t* __restrict__ WmixT, ushort_t* __restrict__ WcatT,
                         ushort_t* __restrict__ WgcbT, ushort_t* __restrict__ WgateT,
                         ushort_t* __restrict__ Wout_rows,
                         ushort_t* __restrict__ xcat_hi, ushort_t* __restrict__ xcat_lo,
                         float* __restrict__ b_cat, float* __restrict__ b_eff) {
    __shared__ float tile[32][33];
    int bid = blockIdx.x;
    int tid = threadIdx.x;
    if (bid < 8192) {
        // cvt_x: x_re|x_im -> xcat hi/lo swizzled
        int g = bid * 256 + tid;
        int m = g >> 8, cidx = g & 255;
        int q = (cidx ^ (m >> 1)) & 3;
        int korig = ((cidx >> 2) << 5) + (q << 3);
        const float* src = (korig < 1024) ? (x_re + (long)m * 1024 + korig)
                                          : (x_im + (long)m * 1024 + korig - 1024);
        float4 v0 = *(const float4*)src;
        float4 v1 = *(const float4*)(src + 4);
        float vv[8] = {v0.x, v0.y, v0.z, v0.w, v1.x, v1.y, v1.z, v1.w};
        union { short8 v; ushort_t u[8]; } H, L;
#pragma unroll
        for (int j = 0; j < 8; j++) {
            ushort_t h = f2bf_rne(vv[j]);
            H.u[j] = h;
            L.u[j] = f2bf_rne(vv[j] - bf2f(h));
        }
        long o = (long)m * 2048 + cidx * 8;
        *(short8*)&xcat_hi[o] = H.v;
        *(short8*)&xcat_lo[o] = L.v;
    } else if (bid < 12288) {
        int j = bid - 8192;
        transpose_job(W_mix, 2048, 2048, WmixT, j & 63, j >> 6, tid, tile);
    } else if (bid < 16384) {
        int j = bid - 12288;
        transpose_job(W_out, 2048, 2048, WcatT, j & 63, j >> 6, tid, tile);
    } else if (bid < 20480) {
        int j = bid - 16384;
        transpose_job(W_gc + 2048ull * 2048ull, 2048, 2048, WgcbT, j & 63, j >> 6, tid, tile);
    } else if (bid < 22528) {
        int j = bid - 20480;
        transpose_job(W_gate, 2048, 1024, WgateT, j & 31, j >> 5, tid, tile);
    } else if (bid < 24576) {
        // cvt_rows(W_out) -> Wout_rows (swizzled rows)
        int g = (bid - 22528) * 256 + tid;
        int m = g >> 8, cidx = g & 255;
        int q = (cidx ^ (m >> 1)) & 3;
        int korig = ((cidx >> 2) << 5) + (q << 3);
        const float* p = W_out + (long)m * 2048 + korig;
        float4 v0 = *(const float4*)p;
        float4 v1 = *(const float4*)(p + 4);
        float vv[8] = {v0.x, v0.y, v0.z, v0.w, v1.x, v1.y, v1.z, v1.w};
        union { short8 v; ushort_t u[8]; } H;
#pragma unroll
        for (int j2 = 0; j2 < 8; j2++) H.u[j2] = f2bf_rne(vv[j2]);
        *(short8*)&Wout_rows[(long)m * 2048 + cidx * 8] = H.v;
    } else {
        int idx = (bid - 24576) * 256 + tid;
        if (idx < 2048) b_cat[idx] = b_out[idx];
        else if (idx < 3072) b_cat[idx] = b_gate[idx - 2048];
        else if (idx < 5120) b_eff[idx - 3072] = b_gc[idx - 3072];
    }
}

// ---------------- k-sliced gemv with atomic reduce (out must be pre-initialized) ----------------
__global__ void gemv_atomic(const float* __restrict__ v, const float* __restrict__ W,
                            float* __restrict__ out, int K, int N) {
    int n = blockIdx.x * 256 + threadIdx.x;
    int kn = K >> 3;
    int k0 = blockIdx.y * kn;
    float s = 0.f;
    for (int k = k0; k < k0 + kn; k++) s += v[k] * W[(long)k * N + n];
    atomicAdd(&out[n], s);
}

// ---------------- GEMM: C = A @ B^T (+Cadd)(+bias)(out-mode) ----------------
// SPLIT: A hi+lo (2 MFMA terms). B hi only.
// OUTMODE 0: f32. 1: f32, sigmoid-gate for col0>=2048. 2: bf16 swizzled rows.
template <bool SPLIT, int OUTMODE, bool ADDM>
__global__ __launch_bounds__(256, 3) void gemm_bf16(
    const ushort_t* __restrict__ Ahi, const ushort_t* __restrict__ Alo,
    const ushort_t* __restrict__ Bhi,
    const float* __restrict__ bias,
    const float* __restrict__ Cadd, int ldadd,
    void* __restrict__ Cout, long ldc, int K) {
    constexpr int NS = SPLIT ? 3 : 2;
    __shared__ ushort_t lds[2][NS][128 * 32];

    const int tid = threadIdx.x;
    const int lane = tid & 63;
    const int wave = tid >> 6;
    const int wr = wave >> 1, wc = wave & 1;
    const int lr = lane & 15, kc = lane >> 4;
    // XCD-aware bijective swizzle (nwg % 8 == 0 for all our grids)
    const int nwg = gridDim.x * gridDim.y;
    const int orig = blockIdx.y * gridDim.x + blockIdx.x;
    const int q8 = nwg >> 3;
    const int w = (orig & 7) * q8 + (orig >> 3);
    const int row0 = (w / gridDim.x) * 128, col0 = (w % gridDim.x) * 128;
    const int sr = tid >> 2, sq = tid & 3;

    f32x4 acc[4][4] = {};

    auto stage = [&](int buf, int kt) {
        const long kbase = (long)kt * 32 + sq * 8;
#pragma unroll
        for (int j = 0; j < 2; j++) {
            gld16(Ahi + (long)(row0 + j * 64 + sr) * K + kbase, &lds[buf][0][(j * 256 + tid) * 8]);
            if constexpr (SPLIT)
                gld16(Alo + (long)(row0 + j * 64 + sr) * K + kbase, &lds[buf][1][(j * 256 + tid) * 8]);
        }
#pragma unroll
        for (int j = 0; j < 2; j++)
            gld16(Bhi + (long)(col0 + j * 64 + sr) * K + kbase, &lds[buf][NS - 1][(j * 256 + tid) * 8]);
    };

    const int nkt = K >> 5;
    stage(0, 0);
    __syncthreads();
    int cur = 0;
    for (int kt = 0; kt < nkt; kt++) {
        if (kt + 1 < nkt) stage(cur ^ 1, kt + 1);

        short8 ahi[4], bhi[4], alo[4];
#pragma unroll
        for (int mi = 0; mi < 4; mi++) {
            int r = wr * 64 + mi * 16 + lr;
            int idx = (r * 32 + kc * 8) ^ (((r >> 1) & 3) << 3);
            ahi[mi] = *(const short8*)&lds[cur][0][idx];
            if constexpr (SPLIT) alo[mi] = *(const short8*)&lds[cur][1][idx];
        }
#pragma unroll
        for (int ni = 0; ni < 4; ni++) {
            int r = wc * 64 + ni * 16 + lr;
            int idx = (r * 32 + kc * 8) ^ (((r >> 1) & 3) << 3);
            bhi[ni] = *(const short8*)&lds[cur][NS - 1][idx];
        }
#pragma unroll
        for (int mi = 0; mi < 4; mi++)
#pragma unroll
            for (int ni = 0; ni < 4; ni++)
                acc[mi][ni] = __builtin_amdgcn_mfma_f32_16x16x32_bf16(ahi[mi], bhi[ni], acc[mi][ni], 0, 0, 0);
        if constexpr (SPLIT) {
#pragma unroll
            for (int mi = 0; mi < 4; mi++)
#pragma unroll
                for (int ni = 0; ni < 4; ni++)
                    acc[mi][ni] = __builtin_amdgcn_mfma_f32_16x16x32_bf16(alo[mi], bhi[ni], acc[mi][ni], 0, 0, 0);
        }
        __syncthreads();
        cur ^= 1;
    }

    const bool gate_blk = (OUTMODE == 1) && (col0 >= 2048);
    float bv[4];
#pragma unroll
    for (int ni = 0; ni < 4; ni++) bv[ni] = bias ? bias[col0 + wc * 64 + ni * 16 + lr] : 0.f;
#pragma unroll
    for (int mi = 0; mi < 4; mi++) {
        int rbase = row0 + wr * 64 + mi * 16 + kc * 4;
#pragma unroll
        for (int ni = 0; ni < 4; ni++) {
            int c = col0 + wc * 64 + ni * 16 + lr;
#pragma unroll
            for (int i = 0; i < 4; i++) {
                float v = acc[mi][ni][i] + bv[ni];
                if constexpr (ADDM) v += Cadd[(long)(rbase + i) * ldadd + c];
                if constexpr (OUTMODE == 2) {
                    ((ushort_t*)Cout)[(long)(rbase + i) * ldc + swz_col(rbase + i, c)] = f2bf_rne(v);
                } else {
                    if constexpr (OUTMODE == 1) {
                        if (gate_blk) v = 0.98f / (1.0f + expf(-v)) + 0.01f;
                    }
                    ((float*)Cout)[(long)(rbase + i) * ldc + c] = v;
                }
            }
        }
    }
}

// ---------------- scan ----------------
__device__ __forceinline__ void step_coefs(float lre, float lim, float dt,
                                           float& are, float& aim,
                                           float& fre, float& fim) {
    float zr = lre * dt, zi = lim * dt;
    float ex = __expf(zr);
    float er = ex - 1.0f;
    float hh = 0.5f * zi;
    float s = __sinf(hh), c = __cosf(hh);
    float s2s = 2.0f * s * s;
    float cy = 1.0f - s2s;
    float sy = 2.0f * s * c;
    are = ex * cy;
    aim = ex * sy;
    float nr = er * cy - s2s;
    float ni = ex * sy;
    float r2 = zr * zr + zi * zi;
    float pr, pi;
    if (r2 > 1e-14f) {
        float inv = 1.0f / r2;
        pr = (nr * zr + ni * zi) * inv;
        pi = (ni * zr - nr * zi) * inv;
    } else {
        pr = 1.0f + 0.5f * zr;
        pi = 0.5f * zi;
    }
    fre = dt * pr;
    fim = dt * pi;
}

__device__ __forceinline__ void lam_of(const float* dre, const float* dim, int d,
                                       float& lre, float& lim) {
    float x = dre[d];
    float sp = fmaxf(x, 0.0f) + log1pf(expf(-fabsf(x)));
    lre = -sp;
    lim = dim[d];
}

__global__ void scan_phase1(const float* __restrict__ x_in,
                            const float* __restrict__ dt_seq,
                            const float* __restrict__ decay_re,
                            const float* __restrict__ decay_im,
                            float4* __restrict__ S) {
    int gw = (blockIdx.x * blockDim.x + threadIdx.x) >> 6;
    int lane = threadIdx.x & 63;
    int d64 = gw & 15;
    int c = (gw >> 4) & (NC - 1);
    int b = gw >> 10;
    int d = d64 * 64 + lane;
    float lre, lim;
    lam_of(decay_re, decay_im, d, lre, lim);
    float Are = 1.f, Aim = 0.f, Bre = 0.f, Bim = 0.f;
    for (int j = 0; j < CT; j++) {
        int t = c * CT + j;
        float dt = dt_seq[b * T_SEQ + t];
        float are, aim, fre, fim;
        step_coefs(lre, lim, dt, are, aim, fre, fim);
        size_t off = ((size_t)(b * T_SEQ + t)) * 2048;
        float xr = x_in[off + d];
        float xi = x_in[off + 1024 + d];
        float xsr = xr * fre - xi * fim;
        float xsi = xr * fim + xi * fre;
        float nbr = are * Bre - aim * Bim + xsr;
        float nbi = are * Bim + aim * Bre + xsi;
        Bre = nbr; Bim = nbi;
        float nar = are * Are - aim * Aim;
        float nai = are * Aim + aim * Are;
        Are = nar; Aim = nai;
    }
    S[(size_t)(b * NC + c) * D_DIM + d] = make_float4(Are, Aim, Bre, Bim);
}

__global__ void scan_phase2(const float4* __restrict__ S,
                            const float* __restrict__ h0_re,
                            const float* __restrict__ h0_im,
                            float2* __restrict__ Pre) {
    int idx = blockIdx.x * blockDim.x + threadIdx.x;
    int b = idx >> 10, d = idx & 1023;
    float Are = 1.f, Aim = 0.f;
    float Bre = h0_re[d], Bim = h0_im[d];
    for (int c = 0; c < NC; c++) {
        Pre[(size_t)(b * NC + c) * D_DIM + d] = make_float2(Bre, Bim);
        float4 s = S[(size_t)(b * NC + c) * D_DIM + d];
        float nAre = s.x * Are - s.y * Aim;
        float nAim = s.x * Aim + s.y * Are;
        float nBre = s.x * Bre - s.y * Bim + s.z;
        float nBim = s.x * Bim + s.y * Bre + s.w;
        Are = nAre; Aim = nAim; Bre = nBre; Bim = nBim;
    }
}

__global__ void scan_phase3(const float* __restrict__ x_in,
                            const float* __restrict__ dt_seq,
                            const float* __restrict__ decay_re,
                            const float* __restrict__ decay_im,
                            const float2* __restrict__ Pre,
                            ushort_t* __restrict__ sthi,
                            ushort_t* __restrict__ stlo) {
    int gw = (blockIdx.x * blockDim.x + threadIdx.x) >> 6;
    int lane = threadIdx.x & 63;
    int d64 = gw & 15;
    int c = (gw >> 4) & (NC - 1);
    int b = gw >> 10;
    int d = d64 * 64 + lane;
    float lre, lim;
    lam_of(decay_re, decay_im, d, lre, lim);
    float2 h = Pre[(size_t)(b * NC + c) * D_DIM + d];
    float hre = h.x, him = h.y;
    for (int j = 0; j < CT; j++) {
        int t = c * CT + j;
        int m = b * T_SEQ + t;
        float dt = dt_seq[m];
        float are, aim, fre, fim;
        step_coefs(lre, lim, dt, are, aim, fre, fim);
        size_t off = ((size_t)m) * 2048;
        float xr = x_in[off + d];
        float xi = x_in[off + 1024 + d];
        float xsr = xr * fre - xi * fim;
        float xsi = xr * fim + xi * fre;
        float nre = are * hre - aim * him + xsr;
        float nim = are * him + aim * hre + xsi;
        hre = nre; him = nim;
        long idx = (long)m * 2048 + swz_col(m, d);
        ushort_t hr = f2bf_rne(hre);
        ushort_t hi2 = f2bf_rne(him);
        sthi[idx] = hr;
        sthi[idx + 1024] = hi2;
        stlo[idx] = f2bf_rne(hre - bf2f(hr));
        stlo[idx + 1024] = f2bf_rne(him - bf2f(hi2));
    }
}

extern "C" void kernel_launch(void* const* d_in, const int* in_sizes, int n_in,
                              void* d_out, int out_size, void* d_ws, size_t ws_size,
                              hipStream_t stream) {
    const float* x_re = (const float*)d_in[0];
    const float* x_im = (const float*)d_in[1];
    const float* dt_seq = (const float*)d_in[2];
    const float* decay_re = (const float*)d_in[3];
    const float* decay_im = (const float*)d_in[4];
    const float* h0_re = (const float*)d_in[5];
    const float* h0_im = (const float*)d_in[6];
    const float* W_mix = (const float*)d_in[7];
    const float* b_mix = (const float*)d_in[8];
    const float* W_out = (const float*)d_in[9];
    const float* b_out = (const float*)d_in[10];
    const float* W_gc = (const float*)d_in[11];
    const float* b_gc = (const float*)d_in[12];
    const float* W_gate = (const float*)d_in[13];
    const float* b_gate = (const float*)d_in[14];
    float* out = (float*)d_out;

    char* ws = (char*)d_ws;
    const unsigned long MB = 1048576ull;
    // x_in region (64 MB), transiently aliased by weight-fold intermediates (all dead
    // before the mix GEMM writes x_in):
    float* x_in = (float*)ws;
    ushort_t* Wout_rows = (ushort_t*)ws;               // 8 MB
    ushort_t* WgcbT = (ushort_t*)(ws + 8 * MB);        // 8 MB
    ushort_t* WgateT = (ushort_t*)(ws + 16 * MB);      // 4 MB
    ushort_t* tmp1_hi = (ushort_t*)(ws + 20 * MB);     // 8 MB
    // xcat -> state (time-aliased: xcat dead after mix GEMM, before scan_phase3)
    ushort_t* xcat_hi = (ushort_t*)(ws + 64 * MB);     // 32 MB
    ushort_t* xcat_lo = (ushort_t*)(ws + 96 * MB);     // 32 MB
    ushort_t* state_hi = xcat_hi;
    ushort_t* state_lo = xcat_lo;
    float4* S = (float4*)(ws + 128 * MB);              // 4 MB
    float2* Pre = (float2*)(ws + 132 * MB);            // 2 MB
    ushort_t* WmixT = (ushort_t*)(ws + 134 * MB);      // 8 MB
    ushort_t* WcatT = (ushort_t*)(ws + 142 * MB);      // 12 MB (3072 x 2048)
    float* b_cat = (float*)(ws + 154 * MB);            // 12 KB
    float* b_eff = (float*)(ws + 154 * MB + 16384);    // 8 KB

    dim3 blk(256);

    // 1. all transposes/conversions/bias-inits in one launch
    prep_all<<<dim3(24596), blk, 0, stream>>>(
        W_mix, W_out, W_gc, W_gate, x_re, x_im, b_out, b_gate, b_gc,
        WmixT, WcatT, WgcbT, WgateT, Wout_rows, xcat_hi, xcat_lo, b_cat, b_eff);

    // 2. b_eff += b_out @ W_gc_bot   (b_eff pre-init to b_gc)
    gemv_atomic<<<dim3(8, 8), blk, 0, stream>>>(b_out, W_gc + 2048ull * 2048ull, b_eff, 2048, 2048);

    // 3. tmp1 = W_out @ W_gc_bot + W_gc_top  -> bf16 swizzled rows
    gemm_bf16<false, 2, true><<<dim3(16, 16), blk, 0, stream>>>(
        Wout_rows, nullptr, WgcbT, nullptr, W_gc, 2048, tmp1_hi, 2048, 2048);

    // 4. W_totalT = W_gateT @ tmp1T  -> WcatT rows 2048..3071 (bf16 swizzled)
    gemm_bf16<false, 2, false><<<dim3(16, 8), blk, 0, stream>>>(
        WgateT, nullptr, tmp1_hi, nullptr, nullptr, 0,
        WcatT + 2048ull * 2048ull, 2048, 2048);

    // 5. b_cat[2048:] += b_eff @ W_gate   (pre-init to b_gate)
    gemv_atomic<<<dim3(4, 8), blk, 0, stream>>>(b_eff, W_gate, b_cat + 2048, 2048, 1024);

    // 6. x_in = xcat @ W_mix + b_mix
    gemm_bf16<true, 0, false><<<dim3(16, 64), blk, 0, stream>>>(
        xcat_hi, xcat_lo, WmixT, b_mix, nullptr, 0, x_in, 2048, 2048);

    // 7-9. scan
    scan_phase1<<<dim3(1024), blk, 0, stream>>>(x_in, dt_seq, decay_re, decay_im, S);
    scan_phase2<<<dim3(16), blk, 0, stream>>>(S, h0_re, h0_im, Pre);
    scan_phase3<<<dim3(1024), blk, 0, stream>>>(x_in, dt_seq, decay_re, decay_im, Pre,
                                                state_hi, state_lo);

    // 10. [src | gate] = state @ [W_outT | W_totalT]^T + b_cat
    gemm_bf16<true, 1, false><<<dim3(24, 64), blk, 0, stream>>>(
        state_hi, state_lo, WcatT, b_cat, nullptr, 0, out, 3072, 2048);
}

// Round 5
// 507.596 us; speedup vs baseline: 3.2991x; 1.2291x over previous
//
#include <hip/hip_runtime.h>

typedef __attribute__((ext_vector_type(8))) short short8;
typedef __attribute__((ext_vector_type(4))) float f32x4;
typedef unsigned short ushort_t;

#define T_SEQ 2048
#define D_DIM 1024
#define M_ROWS 8192
#define CT 32
#define NC (T_SEQ / CT)

__device__ __forceinline__ unsigned short f2bf_rne(float v) {
    unsigned int u = __float_as_uint(v);
    unsigned int r = (u + 0x7fffu + ((u >> 16) & 1u)) >> 16;
    return (unsigned short)r;
}
__device__ __forceinline__ float bf2f(unsigned short u) {
    return __uint_as_float(((unsigned int)u) << 16);
}
__device__ __forceinline__ int swz_col(int m, int k) {
    return (k & ~31) | ((((k >> 3) ^ (m >> 1)) & 3) << 3) | (k & 7);
}

__device__ __forceinline__ void gld16(const ushort_t* g, ushort_t* l) {
    __builtin_amdgcn_global_load_lds(
        (const __attribute__((address_space(1))) unsigned int*)g,
        (__attribute__((address_space(3))) unsigned int*)l, 16, 0, 0);
}

// ---------------- prep_all: all transposes + cvt_x + cvt_rows + bias init ----------------
__device__ __forceinline__ void transpose_job(const float* __restrict__ W, int K, int N,
                                              ushort_t* __restrict__ hi, int bx, int by,
                                              int tid, float (*tile)[33]) {
    int kt = by * 32, nt = bx * 32;
    int c = tid & 31, r0 = tid >> 5;
#pragma unroll
    for (int i = 0; i < 4; i++)
        tile[r0 + i * 8][c] = W[(long)(kt + r0 + i * 8) * N + nt + c];
    __syncthreads();
#pragma unroll
    for (int i = 0; i < 4; i++) {
        int n = r0 + i * 8;
        int m = nt + n;
        float v = tile[c][n];
        int q = ((c >> 3) ^ (m >> 1)) & 3;
        hi[(long)m * K + kt + (q << 3) + (c & 7)] = f2bf_rne(v);
    }
}

__global__ void prep_all(const float* __restrict__ W_mix, const float* __restrict__ W_out,
                         const float* __restrict__ W_gc, const float* __restrict__ W_gate,
                         const float* __restrict__ x_re, const float* __restrict__ x_im,
                         const float* __restrict__ b_out, const float* __restrict__ b_gate,
                         const float* __restrict__ b_gc,
                         ushort_t* __restrict__ WmixT, ushort_t* __restrict__ WcatT,
                         ushort_t* __restrict__ WgcbT, ushort_t* __restrict__ WgateT,
                         ushort_t* __restrict__ Wout_rows,
                         ushort_t* __restrict__ xcat_hi,
                         float* __restrict__ b_cat, float* __restrict__ b_eff) {
    __shared__ float tile[32][33];
    int bid = blockIdx.x;
    int tid = threadIdx.x;
    if (bid < 8192) {
        // cvt_x: x_re|x_im -> xcat bf16 swizzled
        int g = bid * 256 + tid;
        int m = g >> 8, cidx = g & 255;
        int q = (cidx ^ (m >> 1)) & 3;
        int korig = ((cidx >> 2) << 5) + (q << 3);
        const float* src = (korig < 1024) ? (x_re + (long)m * 1024 + korig)
                                          : (x_im + (long)m * 1024 + korig - 1024);
        float4 v0 = *(const float4*)src;
        float4 v1 = *(const float4*)(src + 4);
        float vv[8] = {v0.x, v0.y, v0.z, v0.w, v1.x, v1.y, v1.z, v1.w};
        union { short8 v; ushort_t u[8]; } H;
#pragma unroll
        for (int j = 0; j < 8; j++) H.u[j] = f2bf_rne(vv[j]);
        *(short8*)&xcat_hi[(long)m * 2048 + cidx * 8] = H.v;
    } else if (bid < 12288) {
        int j = bid - 8192;
        transpose_job(W_mix, 2048, 2048, WmixT, j & 63, j >> 6, tid, tile);
    } else if (bid < 16384) {
        int j = bid - 12288;
        transpose_job(W_out, 2048, 2048, WcatT, j & 63, j >> 6, tid, tile);
    } else if (bid < 20480) {
        int j = bid - 16384;
        transpose_job(W_gc + 2048ull * 2048ull, 2048, 2048, WgcbT, j & 63, j >> 6, tid, tile);
    } else if (bid < 22528) {
        int j = bid - 20480;
        transpose_job(W_gate, 2048, 1024, WgateT, j & 31, j >> 5, tid, tile);
    } else if (bid < 24576) {
        // cvt_rows(W_out) -> Wout_rows (swizzled rows)
        int g = (bid - 22528) * 256 + tid;
        int m = g >> 8, cidx = g & 255;
        int q = (cidx ^ (m >> 1)) & 3;
        int korig = ((cidx >> 2) << 5) + (q << 3);
        const float* p = W_out + (long)m * 2048 + korig;
        float4 v0 = *(const float4*)p;
        float4 v1 = *(const float4*)(p + 4);
        float vv[8] = {v0.x, v0.y, v0.z, v0.w, v1.x, v1.y, v1.z, v1.w};
        union { short8 v; ushort_t u[8]; } H;
#pragma unroll
        for (int j2 = 0; j2 < 8; j2++) H.u[j2] = f2bf_rne(vv[j2]);
        *(short8*)&Wout_rows[(long)m * 2048 + cidx * 8] = H.v;
    } else {
        int idx = (bid - 24576) * 256 + tid;
        if (idx < 2048) b_cat[idx] = b_out[idx];
        else if (idx < 3072) b_cat[idx] = b_gate[idx - 2048];
        else if (idx < 5120) b_eff[idx - 3072] = b_gc[idx - 3072];
    }
}

// ---------------- k-sliced gemv with atomic reduce (out must be pre-initialized) ----------------
__global__ void gemv_atomic(const float* __restrict__ v, const float* __restrict__ W,
                            float* __restrict__ out, int K, int N) {
    int n = blockIdx.x * 256 + threadIdx.x;
    int kn = K >> 3;
    int k0 = blockIdx.y * kn;
    float s = 0.f;
    for (int k = k0; k < k0 + kn; k++) s += v[k] * W[(long)k * N + n];
    atomicAdd(&out[n], s);
}

// ---------------- GEMM: C = A @ B^T (+Cadd)(+bias)(out-mode), plain bf16 ----------------
// OUTMODE 0: f32. 1: f32, sigmoid-gate for col0>=2048. 2: bf16 swizzled rows.
template <int OUTMODE, bool ADDM>
__global__ __launch_bounds__(256, 4) void gemm_bf16(
    const ushort_t* __restrict__ Ahi,
    const ushort_t* __restrict__ Bhi,
    const float* __restrict__ bias,
    const float* __restrict__ Cadd, int ldadd,
    void* __restrict__ Cout, long ldc, int K) {
    __shared__ ushort_t lds[2][2][128 * 32];

    const int tid = threadIdx.x;
    const int lane = tid & 63;
    const int wave = tid >> 6;
    const int wr = wave >> 1, wc = wave & 1;
    const int lr = lane & 15, kc = lane >> 4;
    // XCD-aware bijective swizzle (nwg % 8 == 0 for all our grids)
    const int nwg = gridDim.x * gridDim.y;
    const int orig = blockIdx.y * gridDim.x + blockIdx.x;
    const int q8 = nwg >> 3;
    const int w = (orig & 7) * q8 + (orig >> 3);
    const int row0 = (w / gridDim.x) * 128, col0 = (w % gridDim.x) * 128;
    const int sr = tid >> 2, sq = tid & 3;

    f32x4 acc[4][4] = {};

    auto stage = [&](int buf, int kt) {
        const long kbase = (long)kt * 32 + sq * 8;
#pragma unroll
        for (int j = 0; j < 2; j++)
            gld16(Ahi + (long)(row0 + j * 64 + sr) * K + kbase, &lds[buf][0][(j * 256 + tid) * 8]);
#pragma unroll
        for (int j = 0; j < 2; j++)
            gld16(Bhi + (long)(col0 + j * 64 + sr) * K + kbase, &lds[buf][1][(j * 256 + tid) * 8]);
    };

    const int nkt = K >> 5;
    stage(0, 0);
    __syncthreads();
    int cur = 0;
    for (int kt = 0; kt < nkt; kt++) {
        if (kt + 1 < nkt) stage(cur ^ 1, kt + 1);

        short8 ahi[4], bhi[4];
#pragma unroll
        for (int mi = 0; mi < 4; mi++) {
            int r = wr * 64 + mi * 16 + lr;
            int idx = (r * 32 + kc * 8) ^ (((r >> 1) & 3) << 3);
            ahi[mi] = *(const short8*)&lds[cur][0][idx];
        }
#pragma unroll
        for (int ni = 0; ni < 4; ni++) {
            int r = wc * 64 + ni * 16 + lr;
            int idx = (r * 32 + kc * 8) ^ (((r >> 1) & 3) << 3);
            bhi[ni] = *(const short8*)&lds[cur][1][idx];
        }
#pragma unroll
        for (int mi = 0; mi < 4; mi++)
#pragma unroll
            for (int ni = 0; ni < 4; ni++)
                acc[mi][ni] = __builtin_amdgcn_mfma_f32_16x16x32_bf16(ahi[mi], bhi[ni], acc[mi][ni], 0, 0, 0);
        __syncthreads();
        cur ^= 1;
    }

    const bool gate_blk = (OUTMODE == 1) && (col0 >= 2048);
    float bv[4];
#pragma unroll
    for (int ni = 0; ni < 4; ni++) bv[ni] = bias ? bias[col0 + wc * 64 + ni * 16 + lr] : 0.f;
#pragma unroll
    for (int mi = 0; mi < 4; mi++) {
        int rbase = row0 + wr * 64 + mi * 16 + kc * 4;
#pragma unroll
        for (int ni = 0; ni < 4; ni++) {
            int c = col0 + wc * 64 + ni * 16 + lr;
#pragma unroll
            for (int i = 0; i < 4; i++) {
                float v = acc[mi][ni][i] + bv[ni];
                if constexpr (ADDM) v += Cadd[(long)(rbase + i) * ldadd + c];
                if constexpr (OUTMODE == 2) {
                    ((ushort_t*)Cout)[(long)(rbase + i) * ldc + swz_col(rbase + i, c)] = f2bf_rne(v);
                } else {
                    if constexpr (OUTMODE == 1) {
                        if (gate_blk) v = 0.98f / (1.0f + expf(-v)) + 0.01f;
                    }
                    ((float*)Cout)[(long)(rbase + i) * ldc + c] = v;
                }
            }
        }
    }
}

// ---------------- scan ----------------
__device__ __forceinline__ void step_coefs(float lre, float lim, float dt,
                                           float& are, float& aim,
                                           float& fre, float& fim) {
    float zr = lre * dt, zi = lim * dt;
    float ex = __expf(zr);
    float er = ex - 1.0f;
    float hh = 0.5f * zi;
    float s = __sinf(hh), c = __cosf(hh);
    float s2s = 2.0f * s * s;
    float cy = 1.0f - s2s;
    float sy = 2.0f * s * c;
    are = ex * cy;
    aim = ex * sy;
    float nr = er * cy - s2s;
    float ni = ex * sy;
    float r2 = zr * zr + zi * zi;
    float pr, pi;
    if (r2 > 1e-14f) {
        float inv = 1.0f / r2;
        pr = (nr * zr + ni * zi) * inv;
        pi = (ni * zr - nr * zi) * inv;
    } else {
        pr = 1.0f + 0.5f * zr;
        pi = 0.5f * zi;
    }
    fre = dt * pr;
    fim = dt * pi;
}

__device__ __forceinline__ void lam_of(const float* dre, const float* dim, int d,
                                       float& lre, float& lim) {
    float x = dre[d];
    float sp = fmaxf(x, 0.0f) + log1pf(expf(-fabsf(x)));
    lre = -sp;
    lim = dim[d];
}

__global__ void scan_phase1(const float* __restrict__ x_in,
                            const float* __restrict__ dt_seq,
                            const float* __restrict__ decay_re,
                            const float* __restrict__ decay_im,
                            float4* __restrict__ S) {
    int gw = (blockIdx.x * blockDim.x + threadIdx.x) >> 6;
    int lane = threadIdx.x & 63;
    int d64 = gw & 15;
    int c = (gw >> 4) & (NC - 1);
    int b = gw >> 10;
    int d = d64 * 64 + lane;
    float lre, lim;
    lam_of(decay_re, decay_im, d, lre, lim);
    float Are = 1.f, Aim = 0.f, Bre = 0.f, Bim = 0.f;
    for (int j = 0; j < CT; j++) {
        int t = c * CT + j;
        float dt = dt_seq[b * T_SEQ + t];
        float are, aim, fre, fim;
        step_coefs(lre, lim, dt, are, aim, fre, fim);
        size_t off = ((size_t)(b * T_SEQ + t)) * 2048;
        float xr = x_in[off + d];
        float xi = x_in[off + 1024 + d];
        float xsr = xr * fre - xi * fim;
        float xsi = xr * fim + xi * fre;
        float nbr = are * Bre - aim * Bim + xsr;
        float nbi = are * Bim + aim * Bre + xsi;
        Bre = nbr; Bim = nbi;
        float nar = are * Are - aim * Aim;
        float nai = are * Aim + aim * Are;
        Are = nar; Aim = nai;
    }
    S[(size_t)(b * NC + c) * D_DIM + d] = make_float4(Are, Aim, Bre, Bim);
}

__global__ void scan_phase2(const float4* __restrict__ S,
                            const float* __restrict__ h0_re,
                            const float* __restrict__ h0_im,
                            float2* __restrict__ Pre) {
    int idx = blockIdx.x * blockDim.x + threadIdx.x;
    int b = idx >> 10, d = idx & 1023;
    float Are = 1.f, Aim = 0.f;
    float Bre = h0_re[d], Bim = h0_im[d];
    for (int c = 0; c < NC; c++) {
        Pre[(size_t)(b * NC + c) * D_DIM + d] = make_float2(Bre, Bim);
        float4 s = S[(size_t)(b * NC + c) * D_DIM + d];
        float nAre = s.x * Are - s.y * Aim;
        float nAim = s.x * Aim + s.y * Are;
        float nBre = s.x * Bre - s.y * Bim + s.z;
        float nBim = s.x * Bim + s.y * Bre + s.w;
        Are = nAre; Aim = nAim; Bre = nBre; Bim = nBim;
    }
}

__global__ void scan_phase3(const float* __restrict__ x_in,
                            const float* __restrict__ dt_seq,
                            const float* __restrict__ decay_re,
                            const float* __restrict__ decay_im,
                            const float2* __restrict__ Pre,
                            ushort_t* __restrict__ sthi) {
    int gw = (blockIdx.x * blockDim.x + threadIdx.x) >> 6;
    int lane = threadIdx.x & 63;
    int d64 = gw & 15;
    int c = (gw >> 4) & (NC - 1);
    int b = gw >> 10;
    int d = d64 * 64 + lane;
    float lre, lim;
    lam_of(decay_re, decay_im, d, lre, lim);
    float2 h = Pre[(size_t)(b * NC + c) * D_DIM + d];
    float hre = h.x, him = h.y;
    for (int j = 0; j < CT; j++) {
        int t = c * CT + j;
        int m = b * T_SEQ + t;
        float dt = dt_seq[m];
        float are, aim, fre, fim;
        step_coefs(lre, lim, dt, are, aim, fre, fim);
        size_t off = ((size_t)m) * 2048;
        float xr = x_in[off + d];
        float xi = x_in[off + 1024 + d];
        float xsr = xr * fre - xi * fim;
        float xsi = xr * fim + xi * fre;
        float nre = are * hre - aim * him + xsr;
        float nim = are * him + aim * hre + xsi;
        hre = nre; him = nim;
        long idx = (long)m * 2048 + swz_col(m, d);
        sthi[idx] = f2bf_rne(hre);
        sthi[idx + 1024] = f2bf_rne(him);
    }
}

extern "C" void kernel_launch(void* const* d_in, const int* in_sizes, int n_in,
                              void* d_out, int out_size, void* d_ws, size_t ws_size,
                              hipStream_t stream) {
    const float* x_re = (const float*)d_in[0];
    const float* x_im = (const float*)d_in[1];
    const float* dt_seq = (const float*)d_in[2];
    const float* decay_re = (const float*)d_in[3];
    const float* decay_im = (const float*)d_in[4];
    const float* h0_re = (const float*)d_in[5];
    const float* h0_im = (const float*)d_in[6];
    const float* W_mix = (const float*)d_in[7];
    const float* b_mix = (const float*)d_in[8];
    const float* W_out = (const float*)d_in[9];
    const float* b_out = (const float*)d_in[10];
    const float* W_gc = (const float*)d_in[11];
    const float* b_gc = (const float*)d_in[12];
    const float* W_gate = (const float*)d_in[13];
    const float* b_gate = (const float*)d_in[14];
    float* out = (float*)d_out;

    char* ws = (char*)d_ws;
    const unsigned long MB = 1048576ull;
    // x_in region (64 MB), transiently aliased by weight-fold intermediates (all dead
    // before the mix GEMM writes x_in):
    float* x_in = (float*)ws;
    ushort_t* Wout_rows = (ushort_t*)ws;               // 8 MB
    ushort_t* WgcbT = (ushort_t*)(ws + 8 * MB);        // 8 MB
    ushort_t* WgateT = (ushort_t*)(ws + 16 * MB);      // 4 MB
    ushort_t* tmp1_hi = (ushort_t*)(ws + 20 * MB);     // 8 MB
    // xcat -> state (time-aliased: xcat dead after mix GEMM, before scan_phase3)
    ushort_t* xcat_hi = (ushort_t*)(ws + 64 * MB);     // 32 MB
    ushort_t* state_hi = xcat_hi;
    float4* S = (float4*)(ws + 128 * MB);              // 4 MB
    float2* Pre = (float2*)(ws + 132 * MB);            // 2 MB
    ushort_t* WmixT = (ushort_t*)(ws + 134 * MB);      // 8 MB
    ushort_t* WcatT = (ushort_t*)(ws + 142 * MB);      // 12 MB (3072 x 2048)
    float* b_cat = (float*)(ws + 154 * MB);            // 12 KB
    float* b_eff = (float*)(ws + 154 * MB + 16384);    // 8 KB

    dim3 blk(256);

    // 1. all transposes/conversions/bias-inits in one launch
    prep_all<<<dim3(24596), blk, 0, stream>>>(
        W_mix, W_out, W_gc, W_gate, x_re, x_im, b_out, b_gate, b_gc,
        WmixT, WcatT, WgcbT, WgateT, Wout_rows, xcat_hi, b_cat, b_eff);

    // 2. b_eff += b_out @ W_gc_bot   (b_eff pre-init to b_gc)
    gemv_atomic<<<dim3(8, 8), blk, 0, stream>>>(b_out, W_gc + 2048ull * 2048ull, b_eff, 2048, 2048);

    // 3. tmp1 = W_out @ W_gc_bot + W_gc_top  -> bf16 swizzled rows
    gemm_bf16<2, true><<<dim3(16, 16), blk, 0, stream>>>(
        Wout_rows, WgcbT, nullptr, W_gc, 2048, tmp1_hi, 2048, 2048);

    // 4. W_totalT = W_gateT @ tmp1T  -> WcatT rows 2048..3071 (bf16 swizzled)
    gemm_bf16<2, false><<<dim3(16, 8), blk, 0, stream>>>(
        WgateT, tmp1_hi, nullptr, nullptr, 0,
        WcatT + 2048ull * 2048ull, 2048, 2048);

    // 5. b_cat[2048:] += b_eff @ W_gate   (pre-init to b_gate)
    gemv_atomic<<<dim3(4, 8), blk, 0, stream>>>(b_eff, W_gate, b_cat + 2048, 2048, 1024);

    // 6. x_in = xcat @ W_mix + b_mix
    gemm_bf16<0, false><<<dim3(16, 64), blk, 0, stream>>>(
        xcat_hi, WmixT, b_mix, nullptr, 0, x_in, 2048, 2048);

    // 7-9. scan
    scan_phase1<<<dim3(1024), blk, 0, stream>>>(x_in, dt_seq, decay_re, decay_im, S);
    scan_phase2<<<dim3(16), blk, 0, stream>>>(S, h0_re, h0_im, Pre);
    scan_phase3<<<dim3(1024), blk, 0, stream>>>(x_in, dt_seq, decay_re, decay_im, Pre,
                                                state_hi);

    // 10. [src | gate] = state @ [W_outT | W_totalT]^T + b_cat
    gemm_bf16<1, false><<<dim3(24, 64), blk, 0, stream>>>(
        state_hi, WcatT, b_cat, nullptr, 0, out, 3072, 2048);
}

// Round 7
// 480.127 us; speedup vs baseline: 3.4879x; 1.0572x over previous
//
#include <hip/hip_runtime.h>

typedef __attribute__((ext_vector_type(8))) short short8;
typedef __attribute__((ext_vector_type(4))) float f32x4;
typedef unsigned short ushort_t;

#define T_SEQ 2048
#define D_DIM 1024
#define M_ROWS 8192
#define CT 32
#define NC (T_SEQ / CT)

__device__ __forceinline__ unsigned short f2bf_rne(float v) {
    unsigned int u = __float_as_uint(v);
    unsigned int r = (u + 0x7fffu + ((u >> 16) & 1u)) >> 16;
    return (unsigned short)r;
}
__device__ __forceinline__ float bf2f(unsigned short u) {
    return __uint_as_float(((unsigned int)u) << 16);
}
__device__ __forceinline__ int swz_col(int m, int k) {
    return (k & ~31) | ((((k >> 3) ^ (m >> 1)) & 3) << 3) | (k & 7);
}

__device__ __forceinline__ void gld16(const ushort_t* g, ushort_t* l) {
    __builtin_amdgcn_global_load_lds(
        (const __attribute__((address_space(1))) unsigned int*)g,
        (__attribute__((address_space(3))) unsigned int*)l, 16, 0, 0);
}

// ---------------- prep_all: all transposes + cvt_x + cvt_rows + bias init ----------------
__device__ __forceinline__ void transpose_job(const float* __restrict__ W, int K, int N,
                                              ushort_t* __restrict__ hi, int bx, int by,
                                              int tid, float (*tile)[33]) {
    int kt = by * 32, nt = bx * 32;
    int c = tid & 31, r0 = tid >> 5;
#pragma unroll
    for (int i = 0; i < 4; i++)
        tile[r0 + i * 8][c] = W[(long)(kt + r0 + i * 8) * N + nt + c];
    __syncthreads();
#pragma unroll
    for (int i = 0; i < 4; i++) {
        int n = r0 + i * 8;
        int m = nt + n;
        float v = tile[c][n];
        int q = ((c >> 3) ^ (m >> 1)) & 3;
        hi[(long)m * K + kt + (q << 3) + (c & 7)] = f2bf_rne(v);
    }
}

__global__ void prep_all(const float* __restrict__ W_mix, const float* __restrict__ W_out,
                         const float* __restrict__ W_gc, const float* __restrict__ W_gate,
                         const float* __restrict__ x_re, const float* __restrict__ x_im,
                         const float* __restrict__ b_out, const float* __restrict__ b_gate,
                         const float* __restrict__ b_gc,
                         ushort_t* __restrict__ WmixT, ushort_t* __restrict__ WcatT,
                         ushort_t* __restrict__ WgcbT, ushort_t* __restrict__ WgateT,
                         ushort_t* __restrict__ Wout_rows,
                         ushort_t* __restrict__ xcat_hi,
                         float* __restrict__ b_cat, float* __restrict__ b_eff) {
    __shared__ float tile[32][33];
    int bid = blockIdx.x;
    int tid = threadIdx.x;
    if (bid < 8192) {
        int g = bid * 256 + tid;
        int m = g >> 8, cidx = g & 255;
        int q = (cidx ^ (m >> 1)) & 3;
        int korig = ((cidx >> 2) << 5) + (q << 3);
        const float* src = (korig < 1024) ? (x_re + (long)m * 1024 + korig)
                                          : (x_im + (long)m * 1024 + korig - 1024);
        float4 v0 = *(const float4*)src;
        float4 v1 = *(const float4*)(src + 4);
        float vv[8] = {v0.x, v0.y, v0.z, v0.w, v1.x, v1.y, v1.z, v1.w};
        union { short8 v; ushort_t u[8]; } H;
#pragma unroll
        for (int j = 0; j < 8; j++) H.u[j] = f2bf_rne(vv[j]);
        *(short8*)&xcat_hi[(long)m * 2048 + cidx * 8] = H.v;
    } else if (bid < 12288) {
        int j = bid - 8192;
        transpose_job(W_mix, 2048, 2048, WmixT, j & 63, j >> 6, tid, tile);
    } else if (bid < 16384) {
        int j = bid - 12288;
        transpose_job(W_out, 2048, 2048, WcatT, j & 63, j >> 6, tid, tile);
    } else if (bid < 20480) {
        int j = bid - 16384;
        transpose_job(W_gc + 2048ull * 2048ull, 2048, 2048, WgcbT, j & 63, j >> 6, tid, tile);
    } else if (bid < 22528) {
        int j = bid - 20480;
        transpose_job(W_gate, 2048, 1024, WgateT, j & 31, j >> 5, tid, tile);
    } else if (bid < 24576) {
        int g = (bid - 22528) * 256 + tid;
        int m = g >> 8, cidx = g & 255;
        int q = (cidx ^ (m >> 1)) & 3;
        int korig = ((cidx >> 2) << 5) + (q << 3);
        const float* p = W_out + (long)m * 2048 + korig;
        float4 v0 = *(const float4*)p;
        float4 v1 = *(const float4*)(p + 4);
        float vv[8] = {v0.x, v0.y, v0.z, v0.w, v1.x, v1.y, v1.z, v1.w};
        union { short8 v; ushort_t u[8]; } H;
#pragma unroll
        for (int j2 = 0; j2 < 8; j2++) H.u[j2] = f2bf_rne(vv[j2]);
        *(short8*)&Wout_rows[(long)m * 2048 + cidx * 8] = H.v;
    } else {
        int idx = (bid - 24576) * 256 + tid;
        if (idx < 2048) b_cat[idx] = b_out[idx];
        else if (idx < 3072) b_cat[idx] = b_gate[idx - 2048];
        else if (idx < 5120) b_eff[idx - 3072] = b_gc[idx - 3072];
    }
}

// ---------------- k-sliced gemv with atomic reduce (out must be pre-initialized) ----------------
__global__ void gemv_atomic(const float* __restrict__ v, const float* __restrict__ W,
                            float* __restrict__ out, int K, int N) {
    int n = blockIdx.x * 256 + threadIdx.x;
    int kn = K >> 3;
    int k0 = blockIdx.y * kn;
    float s = 0.f;
    for (int k = k0; k < k0 + kn; k++) s += v[k] * W[(long)k * N + n];
    atomicAdd(&out[n], s);
}

// ---------------- GEMM: C = A @ B^T (+Cadd)(+bias)(out-mode), plain bf16 ----------------
// 3-buffer LDS rotation, counted vmcnt (T4), one raw barrier per K-step.
// Staging: 4x global_load_lds per thread (16B/lane linear dest - rule #21).
// OUTMODE 0: f32. 1: f32 + sigmoid-gate for col0>=2048. 2: bf16 swizzled rows.
//         3: bf16 plain rows.
template <int OUTMODE, bool ADDM>
__global__ __launch_bounds__(256, 3) void gemm_bf16(
    const ushort_t* __restrict__ Ahi,
    const ushort_t* __restrict__ Bhi,
    const float* __restrict__ bias,
    const float* __restrict__ Cadd, int ldadd,
    void* __restrict__ Cout, long ldc, int K) {
    __shared__ ushort_t lds[3][2][128 * 32];

    const int tid = threadIdx.x;
    const int lane = tid & 63;
    const int wave = tid >> 6;
    const int wr = wave >> 1, wc = wave & 1;
    const int lr = lane & 15, kc = lane >> 4;
    // XCD-aware bijective swizzle (nwg % 8 == 0 for all our grids)
    const int nwg = gridDim.x * gridDim.y;
    const int orig = blockIdx.y * gridDim.x + blockIdx.x;
    const int q8 = nwg >> 3;
    const int w = (orig & 7) * q8 + (orig >> 3);
    const int row0 = (w / gridDim.x) * 128, col0 = (w % gridDim.x) * 128;
    const int sr = tid >> 2, sq = tid & 3;

    f32x4 acc[4][4] = {};

    auto stage = [&](int buf, int kt) {
        const long kbase = (long)kt * 32 + sq * 8;
#pragma unroll
        for (int j = 0; j < 2; j++)
            gld16(Ahi + (long)(row0 + j * 64 + sr) * K + kbase, &lds[buf][0][(j * 256 + tid) * 8]);
#pragma unroll
        for (int j = 0; j < 2; j++)
            gld16(Bhi + (long)(col0 + j * 64 + sr) * K + kbase, &lds[buf][1][(j * 256 + tid) * 8]);
    };

    const int nkt = K >> 5;
    // prologue: tiles 0 and 1 in flight (4 loads each)
    stage(0, 0);
    stage(1, 1);
    int cur = 0;
    for (int kt = 0; kt < nkt; kt++) {
        if (kt + 1 < nkt) {
            asm volatile("s_waitcnt vmcnt(4)" ::: "memory");  // tile kt landed; kt+1's 4 remain
        } else {
            asm volatile("s_waitcnt vmcnt(0)" ::: "memory");
        }
        __builtin_amdgcn_sched_barrier(0);
        __builtin_amdgcn_s_barrier();
        __builtin_amdgcn_sched_barrier(0);
        if (kt + 2 < nkt) stage((cur + 2) % 3, kt + 2);

        short8 ahi[4], bhi[4];
#pragma unroll
        for (int mi = 0; mi < 4; mi++) {
            int r = wr * 64 + mi * 16 + lr;
            int idx = (r * 32 + kc * 8) ^ (((r >> 1) & 3) << 3);
            ahi[mi] = *(const short8*)&lds[cur][0][idx];
        }
#pragma unroll
        for (int ni = 0; ni < 4; ni++) {
            int r = wc * 64 + ni * 16 + lr;
            int idx = (r * 32 + kc * 8) ^ (((r >> 1) & 3) << 3);
            bhi[ni] = *(const short8*)&lds[cur][1][idx];
        }
#pragma unroll
        for (int mi = 0; mi < 4; mi++)
#pragma unroll
            for (int ni = 0; ni < 4; ni++)
                acc[mi][ni] = __builtin_amdgcn_mfma_f32_16x16x32_bf16(ahi[mi], bhi[ni], acc[mi][ni], 0, 0, 0);
        cur = (cur + 1) % 3;
    }

    const bool gate_blk = (OUTMODE == 1) && (col0 >= 2048);
    float bv[4];
#pragma unroll
    for (int ni = 0; ni < 4; ni++) bv[ni] = bias ? bias[col0 + wc * 64 + ni * 16 + lr] : 0.f;
#pragma unroll
    for (int mi = 0; mi < 4; mi++) {
        int rbase = row0 + wr * 64 + mi * 16 + kc * 4;
#pragma unroll
        for (int ni = 0; ni < 4; ni++) {
            int c = col0 + wc * 64 + ni * 16 + lr;
#pragma unroll
            for (int i = 0; i < 4; i++) {
                float v = acc[mi][ni][i] + bv[ni];
                if constexpr (ADDM) v += Cadd[(long)(rbase + i) * ldadd + c];
                if constexpr (OUTMODE == 2) {
                    ((ushort_t*)Cout)[(long)(rbase + i) * ldc + swz_col(rbase + i, c)] = f2bf_rne(v);
                } else if constexpr (OUTMODE == 3) {
                    ((ushort_t*)Cout)[(long)(rbase + i) * ldc + c] = f2bf_rne(v);
                } else {
                    if constexpr (OUTMODE == 1) {
                        if (gate_blk) v = 0.98f / (1.0f + __expf(-v)) + 0.01f;
                    }
                    ((float*)Cout)[(long)(rbase + i) * ldc + c] = v;
                }
            }
        }
    }
}

// ---------------- scan ----------------
__device__ __forceinline__ void step_coefs(float lre, float lim, float dt,
                                           float& are, float& aim,
                                           float& fre, float& fim) {
    float zr = lre * dt, zi = lim * dt;
    float ex = __expf(zr);
    float er = ex - 1.0f;
    float hh = 0.5f * zi;
    float s = __sinf(hh), c = __cosf(hh);
    float s2s = 2.0f * s * s;
    float cy = 1.0f - s2s;
    float sy = 2.0f * s * c;
    are = ex * cy;
    aim = ex * sy;
    float nr = er * cy - s2s;
    float ni = ex * sy;
    float r2 = zr * zr + zi * zi;
    float pr, pi;
    if (r2 > 1e-14f) {
        float inv = 1.0f / r2;
        pr = (nr * zr + ni * zi) * inv;
        pi = (ni * zr - nr * zi) * inv;
    } else {
        pr = 1.0f + 0.5f * zr;
        pi = 0.5f * zi;
    }
    fre = dt * pr;
    fim = dt * pi;
}

__device__ __forceinline__ void lam_of(const float* dre, const float* dim, int d,
                                       float& lre, float& lim) {
    float x = dre[d];
    float sp = fmaxf(x, 0.0f) + log1pf(expf(-fabsf(x)));
    lre = -sp;
    lim = dim[d];
}

__global__ void scan_phase1(const ushort_t* __restrict__ x_in,
                            const float* __restrict__ dt_seq,
                            const float* __restrict__ decay_re,
                            const float* __restrict__ decay_im,
                            float4* __restrict__ S) {
    int gw = (blockIdx.x * blockDim.x + threadIdx.x) >> 6;
    int lane = threadIdx.x & 63;
    int d64 = gw & 15;
    int c = (gw >> 4) & (NC - 1);
    int b = gw >> 10;
    int d = d64 * 64 + lane;
    float lre, lim;
    lam_of(decay_re, decay_im, d, lre, lim);
    float Are = 1.f, Aim = 0.f, Bre = 0.f, Bim = 0.f;
    for (int j = 0; j < CT; j++) {
        int t = c * CT + j;
        float dt = dt_seq[b * T_SEQ + t];
        float are, aim, fre, fim;
        step_coefs(lre, lim, dt, are, aim, fre, fim);
        size_t off = ((size_t)(b * T_SEQ + t)) * 2048;
        float xr = bf2f(x_in[off + d]);
        float xi = bf2f(x_in[off + 1024 + d]);
        float xsr = xr * fre - xi * fim;
        float xsi = xr * fim + xi * fre;
        float nbr = are * Bre - aim * Bim + xsr;
        float nbi = are * Bim + aim * Bre + xsi;
        Bre = nbr; Bim = nbi;
        float nar = are * Are - aim * Aim;
        float nai = are * Aim + aim * Are;
        Are = nar; Aim = nai;
    }
    S[(size_t)(b * NC + c) * D_DIM + d] = make_float4(Are, Aim, Bre, Bim);
}

__global__ void scan_phase2(const float4* __restrict__ S,
                            const float* __restrict__ h0_re,
                            const float* __restrict__ h0_im,
                            float2* __restrict__ Pre) {
    int idx = blockIdx.x * blockDim.x + threadIdx.x;
    int b = idx >> 10, d = idx & 1023;
    float Are = 1.f, Aim = 0.f;
    float Bre = h0_re[d], Bim = h0_im[d];
    for (int c = 0; c < NC; c++) {
        Pre[(size_t)(b * NC + c) * D_DIM + d] = make_float2(Bre, Bim);
        float4 s = S[(size_t)(b * NC + c) * D_DIM + d];
        float nAre = s.x * Are - s.y * Aim;
        float nAim = s.x * Aim + s.y * Are;
        float nBre = s.x * Bre - s.y * Bim + s.z;
        float nBim = s.x * Bim + s.y * Bre + s.w;
        Are = nAre; Aim = nAim; Bre = nBre; Bim = nBim;
    }
}

__global__ void scan_phase3(const ushort_t* __restrict__ x_in,
                            const float* __restrict__ dt_seq,
                            const float* __restrict__ decay_re,
                            const float* __restrict__ decay_im,
                            const float2* __restrict__ Pre,
                            ushort_t* __restrict__ sthi) {
    int gw = (blockIdx.x * blockDim.x + threadIdx.x) >> 6;
    int lane = threadIdx.x & 63;
    int d64 = gw & 15;
    int c = (gw >> 4) & (NC - 1);
    int b = gw >> 10;
    int d = d64 * 64 + lane;
    float lre, lim;
    lam_of(decay_re, decay_im, d, lre, lim);
    float2 h = Pre[(size_t)(b * NC + c) * D_DIM + d];
    float hre = h.x, him = h.y;
    for (int j = 0; j < CT; j++) {
        int t = c * CT + j;
        int m = b * T_SEQ + t;
        float dt = dt_seq[m];
        float are, aim, fre, fim;
        step_coefs(lre, lim, dt, are, aim, fre, fim);
        size_t off = ((size_t)m) * 2048;
        float xr = bf2f(x_in[off + d]);
        float xi = bf2f(x_in[off + 1024 + d]);
        float xsr = xr * fre - xi * fim;
        float xsi = xr * fim + xi * fre;
        float nre = are * hre - aim * him + xsr;
        float nim = are * him + aim * hre + xsi;
        hre = nre; him = nim;
        long idx = (long)m * 2048 + swz_col(m, d);
        sthi[idx] = f2bf_rne(hre);
        sthi[idx + 1024] = f2bf_rne(him);
    }
}

extern "C" void kernel_launch(void* const* d_in, const int* in_sizes, int n_in,
                              void* d_out, int out_size, void* d_ws, size_t ws_size,
                              hipStream_t stream) {
    const float* x_re = (const float*)d_in[0];
    const float* x_im = (const float*)d_in[1];
    const float* dt_seq = (const float*)d_in[2];
    const float* decay_re = (const float*)d_in[3];
    const float* decay_im = (const float*)d_in[4];
    const float* h0_re = (const float*)d_in[5];
    const float* h0_im = (const float*)d_in[6];
    const float* W_mix = (const float*)d_in[7];
    const float* b_mix = (const float*)d_in[8];
    const float* W_out = (const float*)d_in[9];
    const float* b_out = (const float*)d_in[10];
    const float* W_gc = (const float*)d_in[11];
    const float* b_gc = (const float*)d_in[12];
    const float* W_gate = (const float*)d_in[13];
    const float* b_gate = (const float*)d_in[14];
    float* out = (float*)d_out;

    char* ws = (char*)d_ws;
    const unsigned long MB = 1048576ull;
    ushort_t* x_inb = (ushort_t*)ws;                   // 32 MB (bf16 x_in)
    ushort_t* Wout_rows = (ushort_t*)(ws + 32 * MB);   // 8 MB
    ushort_t* WgcbT = (ushort_t*)(ws + 40 * MB);       // 8 MB
    ushort_t* WgateT = (ushort_t*)(ws + 48 * MB);      // 4 MB
    ushort_t* tmp1_hi = (ushort_t*)(ws + 52 * MB);     // 8 MB
    ushort_t* xcat_hi = (ushort_t*)(ws + 64 * MB);     // 32 MB
    ushort_t* state_hi = xcat_hi;                      // time-aliased
    float4* S = (float4*)(ws + 128 * MB);              // 4 MB
    float2* Pre = (float2*)(ws + 132 * MB);            // 2 MB
    ushort_t* WmixT = (ushort_t*)(ws + 134 * MB);      // 8 MB
    ushort_t* WcatT = (ushort_t*)(ws + 142 * MB);      // 12 MB (3072 x 2048)
    float* b_cat = (float*)(ws + 154 * MB);            // 12 KB
    float* b_eff = (float*)(ws + 154 * MB + 16384);    // 8 KB

    dim3 blk(256);

    // 1. all transposes/conversions/bias-inits in one launch
    prep_all<<<dim3(24596), blk, 0, stream>>>(
        W_mix, W_out, W_gc, W_gate, x_re, x_im, b_out, b_gate, b_gc,
        WmixT, WcatT, WgcbT, WgateT, Wout_rows, xcat_hi, b_cat, b_eff);

    // 2. b_eff += b_out @ W_gc_bot   (b_eff pre-init to b_gc)
    gemv_atomic<<<dim3(8, 8), blk, 0, stream>>>(b_out, W_gc + 2048ull * 2048ull, b_eff, 2048, 2048);

    // 3. tmp1 = W_out @ W_gc_bot + W_gc_top  -> bf16 swizzled rows
    gemm_bf16<2, true><<<dim3(16, 16), blk, 0, stream>>>(
        Wout_rows, WgcbT, nullptr, W_gc, 2048, tmp1_hi, 2048, 2048);

    // 4. W_totalT = W_gateT @ tmp1T  -> WcatT rows 2048..3071 (bf16 swizzled)
    gemm_bf16<2, false><<<dim3(16, 8), blk, 0, stream>>>(
        WgateT, tmp1_hi, nullptr, nullptr, 0,
        WcatT + 2048ull * 2048ull, 2048, 2048);

    // 5. b_cat[2048:] += b_eff @ W_gate   (pre-init to b_gate)
    gemv_atomic<<<dim3(4, 8), blk, 0, stream>>>(b_eff, W_gate, b_cat + 2048, 2048, 1024);

    // 6. x_in(bf16) = xcat @ W_mix + b_mix
    gemm_bf16<3, false><<<dim3(16, 64), blk, 0, stream>>>(
        xcat_hi, WmixT, b_mix, nullptr, 0, x_inb, 2048, 2048);

    // 7-9. scan
    scan_phase1<<<dim3(1024), blk, 0, stream>>>(x_inb, dt_seq, decay_re, decay_im, S);
    scan_phase2<<<dim3(16), blk, 0, stream>>>(S, h0_re, h0_im, Pre);
    scan_phase3<<<dim3(1024), blk, 0, stream>>>(x_inb, dt_seq, decay_re, decay_im, Pre,
                                                state_hi);

    // 10. [src | gate] = state @ [W_outT | W_totalT]^T + b_cat
    gemm_bf16<1, false><<<dim3(24, 64), blk, 0, stream>>>(
        state_hi, WcatT, b_cat, nullptr, 0, out, 3072, 2048);
}